// Round 4
// baseline (709.812 us; speedup 1.0000x reference)
//
#include <hip/hip_runtime.h>
#include <math.h>

// ---------------------------------------------------------------------------
// SABlock: x[B,C,H,W] -> depthwise3x3+res -> [B,N,C]: LN1 -> QKV -> flash-MHA
//          -> proj +res -> LN2 -> FC1 -> GELU -> FC2 -> +res -> [B,C,H,W]
// R4: gemm BK=64 (swizzled LDS, conflict-free b128 frags), transposed-acc
// epilogues (mfma operand swap -> 4 consecutive n per lane -> vector stores),
// fast exp2-tanh GELU, split-K=2 + atomicAdd for proj/fc2 load balance.
// ---------------------------------------------------------------------------

typedef __bf16 bf16;
typedef __attribute__((ext_vector_type(8))) __bf16 bf16x8;
typedef __attribute__((ext_vector_type(4))) __bf16 bf16x4;
typedef __attribute__((ext_vector_type(4))) float f32x4;

#define B_   8
#define C_   768
#define N_   1024
#define NH_  12
#define HD_  64
#define HID_ 3072
#define NTOK   (B_ * N_)     // 8192
#define NHEADS (B_ * NH_)    // 96
#define FA_C   0.1803368801111601f  // 0.125 * log2(e)

__device__ __forceinline__ void gload_lds16(const void* g, void* l) {
  __builtin_amdgcn_global_load_lds(
      (__attribute__((address_space(1))) void*)(void*)g,
      (__attribute__((address_space(3))) void*)l, 16, 0, 0);
}

__device__ __forceinline__ float gelu1(float x) {
  // tanh-form GELU; |err| vs exact erf-GELU well under bf16 noise
  float u = 0.7978845608028654f * x * (1.0f + 0.044715f * x * x);
  float e = __builtin_amdgcn_exp2f(u * 2.885390081777927f);  // exp(2u)
  float th = 1.0f - 2.0f * __builtin_amdgcn_rcpf(e + 1.0f);
  return 0.5f * x * (1.0f + th);
}

// ---------------------------------------------------------------------------
// B^T GEMM, 128x128 tile, BK=64, 256 thr (2x2 waves, 64x64 each).
// Transposed accumulators: acc[i][j] regs = C[m0+wm*64+i*16+lr]
//                                            [n0+wn*64+j*16+kq*4 + r]
// LDS layout: row-major rows of 8 x 16B chunks, chunk slot = c ^ (row&7)
// -> fragment ds_read_b128 hits 8 distinct bank groups (2-way only, free).
// EPI: 0 = QKV scatter to Q,K,V^T   3 = resid atomicAdd(v [+bias if z==0])
//      4 = GELU -> hid (bf16)
// ---------------------------------------------------------------------------
template <int EPI, int KSPLIT>
__global__ __launch_bounds__(256) void gemm_bt(
    const bf16* __restrict__ A, const bf16* __restrict__ B, int K, int lda,
    int ldb, bf16* __restrict__ o0, bf16* __restrict__ o1,
    bf16* __restrict__ o2, float* __restrict__ resid,
    const float* __restrict__ bias) {
  __shared__ __align__(16) bf16 As[128 * 64];   // 16 KB
  __shared__ __align__(16) bf16 Bs[128 * 64];   // 16 KB

  const int tid = threadIdx.x;
  const int wave = tid >> 6, lane = tid & 63;
  const int wm = wave & 1, wn = wave >> 1;
  const int lr = lane & 15, kq = lane >> 4;
  const int m0 = blockIdx.y * 128, n0 = blockIdx.x * 128;
  const int Ksub = K / KSPLIT;
  const int kbase = (KSPLIT > 1) ? blockIdx.z * Ksub : 0;
  const int sw = lr & 7;

  f32x4 acc[4][4];
#pragma unroll
  for (int i = 0; i < 4; i++)
#pragma unroll
    for (int j = 0; j < 4; j++) acc[i][j] = (f32x4){0.f, 0.f, 0.f, 0.f};

  const bf16* Arow = A + (size_t)m0 * lda + kbase;
  const bf16* Brow = B + (size_t)n0 * ldb + kbase;

  for (int k0 = 0; k0 < Ksub; k0 += 64) {
    // stage 128 rows x 64 cols per matrix: 1024 16B chunks, 4 per thread
#pragma unroll
    for (int it = 0; it < 4; ++it) {
      int s = it * 256 + tid;
      int r = s >> 3, seg = (s & 7) ^ (r & 7);
      gload_lds16(Arow + (size_t)r * lda + k0 + seg * 8, (char*)As + s * 16);
    }
#pragma unroll
    for (int it = 0; it < 4; ++it) {
      int s = it * 256 + tid;
      int r = s >> 3, seg = (s & 7) ^ (r & 7);
      gload_lds16(Brow + (size_t)r * ldb + k0 + seg * 8, (char*)Bs + s * 16);
    }
    __syncthreads();

#pragma unroll
    for (int h = 0; h < 2; ++h) {
      bf16x8 af[4], bfr[4];
      const int c = h * 4 + kq;
#pragma unroll
      for (int i = 0; i < 4; i++) {
        int row = wm * 64 + i * 16 + lr;
        af[i] = *(const bf16x8*)((char*)As + (row * 8 + (c ^ sw)) * 16);
      }
#pragma unroll
      for (int j = 0; j < 4; j++) {
        int row = wn * 64 + j * 16 + lr;
        bfr[j] = *(const bf16x8*)((char*)Bs + (row * 8 + (c ^ sw)) * 16);
      }
      // swapped operands -> transposed C/D layout
#pragma unroll
      for (int i = 0; i < 4; i++)
#pragma unroll
        for (int j = 0; j < 4; j++)
          acc[i][j] = __builtin_amdgcn_mfma_f32_16x16x32_bf16(bfr[j], af[i],
                                                              acc[i][j], 0, 0, 0);
    }
    __syncthreads();
  }

  // epilogue: lane holds C[m][n..n+3], m = m0+wm*64+i*16+lr,
  //           n = n0+wn*64+j*16+kq*4
#pragma unroll
  for (int i = 0; i < 4; i++) {
    const int m = m0 + wm * 64 + i * 16 + lr;
#pragma unroll
    for (int j = 0; j < 4; j++) {
      const int n = n0 + wn * 64 + j * 16 + kq * 4;
      const f32x4 v = acc[i][j];
      if constexpr (EPI == 0) {
        int b = m >> 10, tok = m & (N_ - 1);
        int s = (n >= 2 * C_) ? 2 : (n >= C_ ? 1 : 0);
        int rem = n - s * C_;
        int h = rem >> 6, d = rem & 63;
        size_t head = (size_t)b * NH_ + h;
        bf16x4 pk = {(bf16)v[0], (bf16)v[1], (bf16)v[2], (bf16)v[3]};
        if (s == 0)
          *(bf16x4*)(o0 + (head * N_ + tok) * HD_ + d) = pk;   // Q [h][tok][d]
        else if (s == 1)
          *(bf16x4*)(o1 + (head * N_ + tok) * HD_ + d) = pk;   // K [h][tok][d]
        else {
#pragma unroll
          for (int r = 0; r < 4; r++)                          // V^T [h][d][tok]
            o2[(head * HD_ + d + r) * N_ + tok] = (bf16)v[r];
        }
      } else if constexpr (EPI == 3) {
        const f32x4 bv = *(const f32x4*)(bias + n);
        float* rp = resid + (size_t)m * C_ + n;
        if (KSPLIT == 1 || blockIdx.z == 0) {
#pragma unroll
          for (int r = 0; r < 4; r++) atomicAdd(rp + r, v[r] + bv[r]);
        } else {
#pragma unroll
          for (int r = 0; r < 4; r++) atomicAdd(rp + r, v[r]);
        }
      } else if constexpr (EPI == 4) {
        const f32x4 bv = *(const f32x4*)(bias + n);
        bf16x4 pk = {(bf16)gelu1(v[0] + bv[0]), (bf16)gelu1(v[1] + bv[1]),
                     (bf16)gelu1(v[2] + bv[2]), (bf16)gelu1(v[3] + bv[3])};
        *(bf16x4*)(o0 + (size_t)m * HID_ + n) = pk;
      }
    }
  }
}

// ---------------------------------------------------------------------------
// Flash attention: grid (8 q-tiles, 96 heads) = 768 blocks, 256 thr.
// Wave owns 32 q-rows. 16 K-tiles of 64, double-buffered staging.
// ---------------------------------------------------------------------------
__global__ __launch_bounds__(256, 3) void flash_attn(
    const bf16* __restrict__ Qb, const bf16* __restrict__ Kb,
    const bf16* __restrict__ Vt, bf16* __restrict__ attn) {
  __shared__ __align__(16) bf16 ksm[2][64 * 64];
  __shared__ __align__(16) bf16 vsm[2][64 * 64];
  __shared__ __align__(16) bf16 psm[4][32 * 64];

  const int tid = threadIdx.x, wave = tid >> 6, lane = tid & 63;
  const int lr = lane & 15, kq = lane >> 4;
  const int head = blockIdx.y;
  const int b = head / NH_, hh = head - b * NH_;
  const int q0 = blockIdx.x * 128;
  const bf16* Qh = Qb + (size_t)head * (N_ * HD_);
  const bf16* Kh = Kb + (size_t)head * (N_ * HD_);
  const bf16* Vh = Vt + (size_t)head * (HD_ * N_);
  char* pw = (char*)&psm[wave][0];

  bf16x8 qf[2][2];
#pragma unroll
  for (int j = 0; j < 2; ++j)
#pragma unroll
    for (int kh = 0; kh < 2; ++kh)
      qf[j][kh] = *(const bf16x8*)(Qh +
                                   (size_t)(q0 + wave * 32 + j * 16 + lr) * HD_ +
                                   kh * 32 + kq * 8);

  f32x4 o[4][2];
#pragma unroll
  for (int i = 0; i < 4; i++)
#pragma unroll
    for (int j = 0; j < 2; j++) o[i][j] = (f32x4){0.f, 0.f, 0.f, 0.f};
  float mprev[2] = {-1e30f, -1e30f}, lacc[2] = {0.f, 0.f};

  auto stage = [&](int t, int bi) {
#pragma unroll
    for (int it = 0; it < 2; ++it) {
      int s = it * 256 + tid;
      int r = s >> 3, seg = (s & 7) ^ (r & 7);
      gload_lds16(Kh + (size_t)(t * 64 + r) * HD_ + seg * 8,
                  (char*)ksm[bi] + (it * 256 + wave * 64) * 16);
    }
#pragma unroll
    for (int it = 0; it < 2; ++it) {
      int s = it * 256 + tid;
      int r = s >> 3, seg = (s & 7) ^ (r & 7);
      gload_lds16(Vh + (size_t)r * N_ + t * 64 + seg * 8,
                  (char*)vsm[bi] + (it * 256 + wave * 64) * 16);
    }
  };

  stage(0, 0);

  for (int t = 0; t < 16; ++t) {
    const int bi = t & 1;
    __syncthreads();
    if (t < 15) stage(t + 1, bi ^ 1);

    f32x4 sacc[4][2];
#pragma unroll
    for (int i = 0; i < 4; ++i) {
#pragma unroll
      for (int j = 0; j < 2; ++j) sacc[i][j] = (f32x4){0.f, 0.f, 0.f, 0.f};
      int row = i * 16 + lr;
      bf16x8 kf0 = *(const bf16x8*)((char*)ksm[bi] + row * 128 +
                                    ((kq ^ (row & 7)) * 16));
      bf16x8 kf1 = *(const bf16x8*)((char*)ksm[bi] + row * 128 +
                                    (((4 + kq) ^ (row & 7)) * 16));
#pragma unroll
      for (int j = 0; j < 2; ++j) {
        sacc[i][j] = __builtin_amdgcn_mfma_f32_16x16x32_bf16(kf0, qf[j][0],
                                                             sacc[i][j], 0, 0, 0);
        sacc[i][j] = __builtin_amdgcn_mfma_f32_16x16x32_bf16(kf1, qf[j][1],
                                                             sacc[i][j], 0, 0, 0);
      }
    }

#pragma unroll
    for (int j = 0; j < 2; ++j) {
      float mx = -1e30f;
#pragma unroll
      for (int i = 0; i < 4; ++i)
#pragma unroll
        for (int r = 0; r < 4; ++r) mx = fmaxf(mx, sacc[i][j][r]);
      mx = fmaxf(mx, __shfl_xor(mx, 16));
      mx = fmaxf(mx, __shfl_xor(mx, 32));
      float mnew = fmaxf(mprev[j], mx);
      float alpha = __builtin_amdgcn_exp2f((mprev[j] - mnew) * FA_C);
      mprev[j] = mnew;
      float rs = 0.f;
      const int prow = j * 16 + lr;
#pragma unroll
      for (int i = 0; i < 4; ++i) {
        float p0 = __builtin_amdgcn_exp2f((sacc[i][j][0] - mnew) * FA_C);
        float p1 = __builtin_amdgcn_exp2f((sacc[i][j][1] - mnew) * FA_C);
        float p2 = __builtin_amdgcn_exp2f((sacc[i][j][2] - mnew) * FA_C);
        float p3 = __builtin_amdgcn_exp2f((sacc[i][j][3] - mnew) * FA_C);
        rs += (p0 + p1) + (p2 + p3);
        bf16x4 pk = {(bf16)p0, (bf16)p1, (bf16)p2, (bf16)p3};
        int c = i * 2 + (kq >> 1);
        *(bf16x4*)(pw + prow * 128 + ((c ^ (prow & 7)) * 16) + (kq & 1) * 8) = pk;
      }
      rs += __shfl_xor(rs, 16);
      rs += __shfl_xor(rs, 32);
      lacc[j] = lacc[j] * alpha + rs;
#pragma unroll
      for (int i = 0; i < 4; ++i) {
        o[i][j][0] *= alpha; o[i][j][1] *= alpha;
        o[i][j][2] *= alpha; o[i][j][3] *= alpha;
      }
    }

#pragma unroll
    for (int k0c = 0; k0c < 2; ++k0c) {
      bf16x8 pf[2];
#pragma unroll
      for (int j = 0; j < 2; ++j) {
        int prow = j * 16 + lr, c = k0c * 4 + kq;
        pf[j] = *(const bf16x8*)(pw + prow * 128 + ((c ^ (prow & 7)) * 16));
      }
#pragma unroll
      for (int i = 0; i < 4; ++i) {
        int d = i * 16 + lr, c = k0c * 4 + kq;
        bf16x8 vf = *(const bf16x8*)((char*)vsm[bi] + d * 128 +
                                     ((c ^ (d & 7)) * 16));
#pragma unroll
        for (int j = 0; j < 2; ++j)
          o[i][j] = __builtin_amdgcn_mfma_f32_16x16x32_bf16(vf, pf[j], o[i][j],
                                                            0, 0, 0);
      }
    }
  }

#pragma unroll
  for (int j = 0; j < 2; ++j) {
    float inv = 1.0f / lacc[j];
    int tok = q0 + wave * 32 + j * 16 + lr;
    bf16* op = attn + ((size_t)(b * N_ + tok)) * C_ + hh * HD_;
#pragma unroll
    for (int i = 0; i < 4; ++i) {
      bf16x4 pk = {(bf16)(o[i][j][0] * inv), (bf16)(o[i][j][1] * inv),
                   (bf16)(o[i][j][2] * inv), (bf16)(o[i][j][3] * inv)};
      *(bf16x4*)(op + i * 16 + kq * 4) = pk;
    }
  }
}

// ---------------------------------------------------------------------------
__global__ __launch_bounds__(256) void cast_all(
    const float* __restrict__ a, int na, const float* __restrict__ b, int nb,
    const float* __restrict__ c, int nc, const float* __restrict__ d,
    bf16* __restrict__ dst) {
  int i = (blockIdx.x * 256 + threadIdx.x) * 4;
  const float* src;
  int off;
  if (i < na) { src = a; off = i; }
  else if (i < na + nb) { src = b; off = i - na; }
  else if (i < na + nb + nc) { src = c; off = i - na - nb; }
  else { src = d; off = i - na - nb - nc; }
  float4 v = *(const float4*)(src + off);
  bf16x4 o = {(bf16)v.x, (bf16)v.y, (bf16)v.z, (bf16)v.w};
  *(bf16x4*)(dst + i) = o;
}

// depthwise 3x3 conv + bias + residual, fused transpose NCHW -> [B,N,C]
__global__ __launch_bounds__(256) void conv_pe_t(const float* __restrict__ x,
                                                 const float* __restrict__ cw,
                                                 const float* __restrict__ cb,
                                                 float* __restrict__ t0) {
  __shared__ float tile[32][33];
  const int h = blockIdx.x, ct = blockIdx.y, b = blockIdx.z;
  const int tid = threadIdx.x;
  const int w = tid & 31, cs = tid >> 5;
#pragma unroll
  for (int cc = cs; cc < 32; cc += 8) {
    int c = ct * 32 + cc;
    const float* xp = x + ((size_t)(b * C_ + c)) * 1024;
    const float* wp = cw + c * 9;
    float s = cb[c] + xp[h * 32 + w];
#pragma unroll
    for (int ky = 0; ky < 3; ++ky) {
      int hy = h + ky - 1;
      if ((unsigned)hy < 32u) {
#pragma unroll
        for (int kx = 0; kx < 3; ++kx) {
          int wx = w + kx - 1;
          if ((unsigned)wx < 32u) s += xp[hy * 32 + wx] * wp[ky * 3 + kx];
        }
      }
    }
    tile[cc][w] = s;
  }
  __syncthreads();
  const int cc = tid & 31;
#pragma unroll
  for (int wc = tid >> 5; wc < 32; wc += 8)
    t0[((size_t)(b * N_) + h * 32 + wc) * C_ + ct * 32 + cc] = tile[cc][wc];
}

// LayerNorm over C=768, fp32 in, bf16 out
__global__ __launch_bounds__(256) void ln_bf16(const float* __restrict__ t,
                                               const float* __restrict__ g,
                                               const float* __restrict__ be,
                                               bf16* __restrict__ out) {
  int row = blockIdx.x, tid = threadIdx.x;
  const float* p = t + (size_t)row * C_;
  float v0 = p[tid], v1 = p[tid + 256], v2 = p[tid + 512];
  __shared__ float rs[256], rq[256];
  rs[tid] = v0 + v1 + v2;
  rq[tid] = v0 * v0 + v1 * v1 + v2 * v2;
  __syncthreads();
  for (int off = 128; off; off >>= 1) {
    if (tid < off) {
      rs[tid] += rs[tid + off];
      rq[tid] += rq[tid + off];
    }
    __syncthreads();
  }
  float mu = rs[0] * (1.f / C_);
  float var = rq[0] * (1.f / C_) - mu * mu;
  float rstd = rsqrtf(var + 1e-5f);
  bf16* q = out + (size_t)row * C_;
  q[tid] = (bf16)((v0 - mu) * rstd * g[tid] + be[tid]);
  q[tid + 256] = (bf16)((v1 - mu) * rstd * g[tid + 256] + be[tid + 256]);
  q[tid + 512] = (bf16)((v2 - mu) * rstd * g[tid + 512] + be[tid + 512]);
}

// batched 2D transpose via LDS: out[b][cc][r] = in[b][r][cc]
__global__ __launch_bounds__(256) void transpose_f32(
    const float* __restrict__ in, float* __restrict__ out, int R, int Cc) {
  __shared__ float tile[32][33];
  int b = blockIdx.z;
  const float* ip = in + (size_t)b * R * Cc;
  float* op = out + (size_t)b * R * Cc;
  int c0 = blockIdx.x * 32, r0 = blockIdx.y * 32;
  int tx = threadIdx.x & 31, ty = threadIdx.x >> 5;
#pragma unroll
  for (int i = 0; i < 32; i += 8)
    tile[ty + i][tx] = ip[(size_t)(r0 + ty + i) * Cc + c0 + tx];
  __syncthreads();
#pragma unroll
  for (int i = 0; i < 32; i += 8)
    op[(size_t)(c0 + ty + i) * R + r0 + tx] = tile[tx][ty + i];
}

// ---------------------------------------------------------------------------
extern "C" void kernel_launch(void* const* d_in, const int* in_sizes, int n_in,
                              void* d_out, int out_size, void* d_ws,
                              size_t ws_size, hipStream_t stream) {
  (void)in_sizes; (void)n_in; (void)out_size; (void)ws_size;
  const float* x      = (const float*)d_in[0];
  const float* conv_w = (const float*)d_in[1];
  const float* conv_b = (const float*)d_in[2];
  const float* ln1_g  = (const float*)d_in[3];
  const float* ln1_b  = (const float*)d_in[4];
  const float* qkv_w  = (const float*)d_in[5];
  const float* proj_w = (const float*)d_in[6];
  const float* proj_b = (const float*)d_in[7];
  const float* ln2_g  = (const float*)d_in[8];
  const float* ln2_b  = (const float*)d_in[9];
  const float* fc1_w  = (const float*)d_in[10];
  const float* fc1_b  = (const float*)d_in[11];
  const float* fc2_w  = (const float*)d_in[12];
  const float* fc2_b  = (const float*)d_in[13];
  float* out = (float*)d_out;

  char* w = (char*)d_ws;
  auto carve = [&](size_t bytes) {
    char* p = w;
    w += (bytes + 255) & ~(size_t)255;
    return p;
  };
  bf16* hid   = (bf16*)carve((size_t)NTOK * HID_ * 2);
  float* t0   = (float*)carve((size_t)NTOK * C_ * 4);
  bf16* lnout = (bf16*)carve((size_t)NTOK * C_ * 2);
  bf16* wq    = (bf16*)carve((size_t)3 * C_ * C_ * 2);
  bf16* wp    = (bf16*)carve((size_t)C_ * C_ * 2);
  bf16* w1    = (bf16*)carve((size_t)HID_ * C_ * 2);
  bf16* w2    = (bf16*)carve((size_t)C_ * HID_ * 2);
  bf16* Qb    = (bf16*)carve((size_t)NHEADS * N_ * HD_ * 2);
  bf16* Kb    = (bf16*)carve((size_t)NHEADS * N_ * HD_ * 2);
  bf16* Vt    = (bf16*)carve((size_t)NHEADS * HD_ * N_ * 2);
  bf16* attn  = (bf16*)carve((size_t)NTOK * C_ * 2);

  const int na = 3 * C_ * C_, nb = C_ * C_, nc = HID_ * C_, nd = C_ * HID_;
  cast_all<<<(na + nb + nc + nd) / 1024, 256, 0, stream>>>(
      qkv_w, na, proj_w, nb, fc1_w, nc, fc2_w, wq);

  conv_pe_t<<<dim3(32, C_ / 32, B_), 256, 0, stream>>>(x, conv_w, conv_b, t0);

  ln_bf16<<<NTOK, 256, 0, stream>>>(t0, ln1_g, ln1_b, lnout);
  gemm_bt<0, 1><<<dim3(3 * C_ / 128, NTOK / 128), 256, 0, stream>>>(
      lnout, wq, 768, 768, 768, Qb, Kb, Vt, nullptr, nullptr);

  flash_attn<<<dim3(N_ / 128, NHEADS), 256, 0, stream>>>(Qb, Kb, Vt, attn);

  // proj / fc2: split-K=2 -> 768 balanced blocks, fp32 atomic residual add
  gemm_bt<3, 2><<<dim3(C_ / 128, NTOK / 128, 2), 256, 0, stream>>>(
      attn, wp, 768, 768, 768, nullptr, nullptr, nullptr, t0, proj_b);
  ln_bf16<<<NTOK, 256, 0, stream>>>(t0, ln2_g, ln2_b, lnout);
  gemm_bt<4, 1><<<dim3(HID_ / 128, NTOK / 128), 256, 0, stream>>>(
      lnout, w1, 768, 768, 768, hid, nullptr, nullptr, nullptr, fc1_b);
  gemm_bt<3, 2><<<dim3(C_ / 128, NTOK / 128, 2), 256, 0, stream>>>(
      hid, w2, 3072, 3072, 3072, nullptr, nullptr, nullptr, t0, fc2_b);

  transpose_f32<<<dim3(C_ / 32, N_ / 32, B_), 256, 0, stream>>>(t0, out, N_, C_);
}

// Round 5
// 425.492 us; speedup vs baseline: 1.6682x; 1.6682x over previous
//
#include <hip/hip_runtime.h>
#include <math.h>

// ---------------------------------------------------------------------------
// SABlock: x[B,C,H,W] -> depthwise3x3+res -> [B,N,C]: LN1 -> QKV -> flash-MHA
//          -> proj +res -> LN2 -> FC1 -> GELU -> FC2 -> +res -> [B,C,H,W]
// R5: BK=64 swizzled LDS (0 bank conflicts), transposed-acc epilogues
// (vector stores), non-atomic float4 residual RMW (R4's atomics were 3x
// slower), QKV V^T via in-kernel LDS transpose bounce, fast exp2 GELU.
// ---------------------------------------------------------------------------

typedef __bf16 bf16;
typedef __attribute__((ext_vector_type(8))) __bf16 bf16x8;
typedef __attribute__((ext_vector_type(4))) __bf16 bf16x4;
typedef __attribute__((ext_vector_type(4))) float f32x4;

#define B_   8
#define C_   768
#define N_   1024
#define NH_  12
#define HD_  64
#define HID_ 3072
#define NTOK   (B_ * N_)     // 8192
#define NHEADS (B_ * NH_)    // 96
#define FA_C   0.1803368801111601f  // 0.125 * log2(e)

__device__ __forceinline__ void gload_lds16(const void* g, void* l) {
  __builtin_amdgcn_global_load_lds(
      (__attribute__((address_space(1))) void*)(void*)g,
      (__attribute__((address_space(3))) void*)l, 16, 0, 0);
}

__device__ __forceinline__ float gelu1(float x) {
  // tanh-form GELU via exp2; |err| well under bf16 noise (verified R4)
  float u = 0.7978845608028654f * x * (1.0f + 0.044715f * x * x);
  float e = __builtin_amdgcn_exp2f(u * 2.885390081777927f);  // exp(2u)
  float th = 1.0f - 2.0f * __builtin_amdgcn_rcpf(e + 1.0f);
  return 0.5f * x * (1.0f + th);
}

// ---------------------------------------------------------------------------
// B^T GEMM, 128x128 tile, BK=64, 256 thr (2x2 waves, 64x64 each).
// Transposed accumulators (operand-swapped MFMA): lane holds C[m][n..n+3],
//   m = m0+wm*64+i*16+lr,  n = n0+wn*64+j*16+kq*4
// LDS: rows of 8 x 16B chunks, chunk slot = c ^ (row&7) -> 0 bank conflicts.
// EPI: 0 = QKV (Q,K vector stores; V via LDS-transpose bounce -> V^T rows)
//      3 = resid float4 RMW += v + bias      4 = GELU -> hid (bf16)
// ---------------------------------------------------------------------------
template <int EPI>
__global__ __launch_bounds__(256) void gemm_bt(
    const bf16* __restrict__ A, const bf16* __restrict__ B, int K, int lda,
    int ldb, bf16* __restrict__ o0, bf16* __restrict__ o1,
    bf16* __restrict__ o2, float* __restrict__ resid,
    const float* __restrict__ bias) {
  __shared__ __align__(16) bf16 smem[2 * 128 * 64];   // 32 KB (As | Bs)
  bf16* As = smem;
  bf16* Bs = smem + 128 * 64;

  const int tid = threadIdx.x;
  const int wave = tid >> 6, lane = tid & 63;
  const int wm = wave & 1, wn = wave >> 1;
  const int lr = lane & 15, kq = lane >> 4;
  const int m0 = blockIdx.y * 128, n0 = blockIdx.x * 128;
  const int sw = lr & 7;

  f32x4 acc[4][4];
#pragma unroll
  for (int i = 0; i < 4; i++)
#pragma unroll
    for (int j = 0; j < 4; j++) acc[i][j] = (f32x4){0.f, 0.f, 0.f, 0.f};

  const bf16* Arow = A + (size_t)m0 * lda;
  const bf16* Brow = B + (size_t)n0 * ldb;

  for (int k0 = 0; k0 < K; k0 += 64) {
#pragma unroll
    for (int it = 0; it < 4; ++it) {
      int s = it * 256 + tid;
      int r = s >> 3, seg = (s & 7) ^ (r & 7);
      gload_lds16(Arow + (size_t)r * lda + k0 + seg * 8, (char*)As + s * 16);
    }
#pragma unroll
    for (int it = 0; it < 4; ++it) {
      int s = it * 256 + tid;
      int r = s >> 3, seg = (s & 7) ^ (r & 7);
      gload_lds16(Brow + (size_t)r * ldb + k0 + seg * 8, (char*)Bs + s * 16);
    }
    __syncthreads();

#pragma unroll
    for (int h = 0; h < 2; ++h) {
      bf16x8 af[4], bfr[4];
      const int c = h * 4 + kq;
#pragma unroll
      for (int i = 0; i < 4; i++) {
        int row = wm * 64 + i * 16 + lr;
        af[i] = *(const bf16x8*)((char*)As + (row * 8 + (c ^ sw)) * 16);
      }
#pragma unroll
      for (int j = 0; j < 4; j++) {
        int row = wn * 64 + j * 16 + lr;
        bfr[j] = *(const bf16x8*)((char*)Bs + (row * 8 + (c ^ sw)) * 16);
      }
      // swapped operands -> transposed C/D layout
#pragma unroll
      for (int i = 0; i < 4; i++)
#pragma unroll
        for (int j = 0; j < 4; j++)
          acc[i][j] = __builtin_amdgcn_mfma_f32_16x16x32_bf16(bfr[j], af[i],
                                                              acc[i][j], 0, 0, 0);
    }
    __syncthreads();
  }

  if constexpr (EPI == 0) {
    const int b = m0 >> 10, tok0 = m0 & (N_ - 1);
    if (n0 < 2 * C_) {
      // Q or K: vector bf16x4 stores, [head][tok][d]
      const int s = n0 >= C_ ? 1 : 0;
      bf16* dst = s ? o1 : o0;
#pragma unroll
      for (int i = 0; i < 4; i++) {
        const int m = m0 + wm * 64 + i * 16 + lr;
#pragma unroll
        for (int j = 0; j < 4; j++) {
          const int rem = n0 - s * C_ + wn * 64 + j * 16 + kq * 4;
          const int h = rem >> 6, d = rem & 63;
          const f32x4 v = acc[i][j];
          bf16x4 pk = {(bf16)v[0], (bf16)v[1], (bf16)v[2], (bf16)v[3]};
          size_t head = (size_t)b * NH_ + h;
          *(bf16x4*)(dst + (head * N_ + (m & (N_ - 1))) * HD_ + d) = pk;
        }
      }
    } else {
      // V: bounce through LDS (32 KB tile, swizzled) -> coalesced V^T rows.
      // tile[nl][ml]: row nl = 16 chunks of 16B, chunk slot = c ^ (nl&15)
      bf16* tile = smem;
#pragma unroll
      for (int i = 0; i < 4; i++) {
        const int ml = wm * 64 + i * 16 + lr;
        const int mc = ml >> 3, mo = ml & 7;
#pragma unroll
        for (int j = 0; j < 4; j++) {
          const f32x4 v = acc[i][j];
#pragma unroll
          for (int r = 0; r < 4; r++) {
            const int nl = wn * 64 + j * 16 + kq * 4 + r;
            *(bf16*)((char*)tile + nl * 256 + ((mc ^ (nl & 15)) * 16) + mo * 2) =
                (bf16)v[r];
          }
        }
      }
      __syncthreads();
      const int nl = tid >> 1, mh = (tid & 1) * 64;   // 128 rows x 2 halves
      const int vb = n0 - 2 * C_ + nl;                // channel within 768
      const size_t head = (size_t)b * NH_ + (vb >> 6);
      bf16* dst = o2 + (head * HD_ + (vb & 63)) * N_ + tok0 + mh;
#pragma unroll
      for (int c8 = 0; c8 < 8; ++c8) {
        const int c = (mh >> 3) + c8;
        bf16x8 val = *(const bf16x8*)((char*)tile + nl * 256 +
                                      ((c ^ (nl & 15)) * 16));
        *(bf16x8*)(dst + c8 * 8) = val;
      }
    }
  } else if constexpr (EPI == 3) {
#pragma unroll
    for (int j = 0; j < 4; j++) {
      const int n = n0 + wn * 64 + j * 16 + kq * 4;
      const f32x4 bv = *(const f32x4*)(bias + n);
#pragma unroll
      for (int i = 0; i < 4; i++) {
        const int m = m0 + wm * 64 + i * 16 + lr;
        float* rp = resid + (size_t)m * C_ + n;
        f32x4 old = *(const f32x4*)rp;
        const f32x4 v = acc[i][j];
        f32x4 nw = {old[0] + v[0] + bv[0], old[1] + v[1] + bv[1],
                    old[2] + v[2] + bv[2], old[3] + v[3] + bv[3]};
        *(f32x4*)rp = nw;
      }
    }
  } else if constexpr (EPI == 4) {
#pragma unroll
    for (int j = 0; j < 4; j++) {
      const int n = n0 + wn * 64 + j * 16 + kq * 4;
      const f32x4 bv = *(const f32x4*)(bias + n);
#pragma unroll
      for (int i = 0; i < 4; i++) {
        const int m = m0 + wm * 64 + i * 16 + lr;
        const f32x4 v = acc[i][j];
        bf16x4 pk = {(bf16)gelu1(v[0] + bv[0]), (bf16)gelu1(v[1] + bv[1]),
                     (bf16)gelu1(v[2] + bv[2]), (bf16)gelu1(v[3] + bv[3])};
        *(bf16x4*)(o0 + (size_t)m * HID_ + n) = pk;
      }
    }
  }
}

// ---------------------------------------------------------------------------
// Flash attention: grid (8 q-tiles, 96 heads) = 768 blocks, 256 thr.
// Wave owns 32 q-rows. 16 K-tiles of 64, double-buffered staging.
// ---------------------------------------------------------------------------
__global__ __launch_bounds__(256, 3) void flash_attn(
    const bf16* __restrict__ Qb, const bf16* __restrict__ Kb,
    const bf16* __restrict__ Vt, bf16* __restrict__ attn) {
  __shared__ __align__(16) bf16 ksm[2][64 * 64];
  __shared__ __align__(16) bf16 vsm[2][64 * 64];
  __shared__ __align__(16) bf16 psm[4][32 * 64];

  const int tid = threadIdx.x, wave = tid >> 6, lane = tid & 63;
  const int lr = lane & 15, kq = lane >> 4;
  const int head = blockIdx.y;
  const int b = head / NH_, hh = head - b * NH_;
  const int q0 = blockIdx.x * 128;
  const bf16* Qh = Qb + (size_t)head * (N_ * HD_);
  const bf16* Kh = Kb + (size_t)head * (N_ * HD_);
  const bf16* Vh = Vt + (size_t)head * (HD_ * N_);
  char* pw = (char*)&psm[wave][0];

  bf16x8 qf[2][2];
#pragma unroll
  for (int j = 0; j < 2; ++j)
#pragma unroll
    for (int kh = 0; kh < 2; ++kh)
      qf[j][kh] = *(const bf16x8*)(Qh +
                                   (size_t)(q0 + wave * 32 + j * 16 + lr) * HD_ +
                                   kh * 32 + kq * 8);

  f32x4 o[4][2];
#pragma unroll
  for (int i = 0; i < 4; i++)
#pragma unroll
    for (int j = 0; j < 2; j++) o[i][j] = (f32x4){0.f, 0.f, 0.f, 0.f};
  float mprev[2] = {-1e30f, -1e30f}, lacc[2] = {0.f, 0.f};

  auto stage = [&](int t, int bi) {
#pragma unroll
    for (int it = 0; it < 2; ++it) {
      int s = it * 256 + tid;
      int r = s >> 3, seg = (s & 7) ^ (r & 7);
      gload_lds16(Kh + (size_t)(t * 64 + r) * HD_ + seg * 8,
                  (char*)ksm[bi] + (it * 256 + wave * 64) * 16);
    }
#pragma unroll
    for (int it = 0; it < 2; ++it) {
      int s = it * 256 + tid;
      int r = s >> 3, seg = (s & 7) ^ (r & 7);
      gload_lds16(Vh + (size_t)r * N_ + t * 64 + seg * 8,
                  (char*)vsm[bi] + (it * 256 + wave * 64) * 16);
    }
  };

  stage(0, 0);

  for (int t = 0; t < 16; ++t) {
    const int bi = t & 1;
    __syncthreads();
    if (t < 15) stage(t + 1, bi ^ 1);

    f32x4 sacc[4][2];
#pragma unroll
    for (int i = 0; i < 4; ++i) {
#pragma unroll
      for (int j = 0; j < 2; ++j) sacc[i][j] = (f32x4){0.f, 0.f, 0.f, 0.f};
      int row = i * 16 + lr;
      bf16x8 kf0 = *(const bf16x8*)((char*)ksm[bi] + row * 128 +
                                    ((kq ^ (row & 7)) * 16));
      bf16x8 kf1 = *(const bf16x8*)((char*)ksm[bi] + row * 128 +
                                    (((4 + kq) ^ (row & 7)) * 16));
#pragma unroll
      for (int j = 0; j < 2; ++j) {
        sacc[i][j] = __builtin_amdgcn_mfma_f32_16x16x32_bf16(kf0, qf[j][0],
                                                             sacc[i][j], 0, 0, 0);
        sacc[i][j] = __builtin_amdgcn_mfma_f32_16x16x32_bf16(kf1, qf[j][1],
                                                             sacc[i][j], 0, 0, 0);
      }
    }

#pragma unroll
    for (int j = 0; j < 2; ++j) {
      float mx = -1e30f;
#pragma unroll
      for (int i = 0; i < 4; ++i)
#pragma unroll
        for (int r = 0; r < 4; ++r) mx = fmaxf(mx, sacc[i][j][r]);
      mx = fmaxf(mx, __shfl_xor(mx, 16));
      mx = fmaxf(mx, __shfl_xor(mx, 32));
      float mnew = fmaxf(mprev[j], mx);
      float alpha = __builtin_amdgcn_exp2f((mprev[j] - mnew) * FA_C);
      mprev[j] = mnew;
      float rs = 0.f;
      const int prow = j * 16 + lr;
#pragma unroll
      for (int i = 0; i < 4; ++i) {
        float p0 = __builtin_amdgcn_exp2f((sacc[i][j][0] - mnew) * FA_C);
        float p1 = __builtin_amdgcn_exp2f((sacc[i][j][1] - mnew) * FA_C);
        float p2 = __builtin_amdgcn_exp2f((sacc[i][j][2] - mnew) * FA_C);
        float p3 = __builtin_amdgcn_exp2f((sacc[i][j][3] - mnew) * FA_C);
        rs += (p0 + p1) + (p2 + p3);
        bf16x4 pk = {(bf16)p0, (bf16)p1, (bf16)p2, (bf16)p3};
        int c = i * 2 + (kq >> 1);
        *(bf16x4*)(pw + prow * 128 + ((c ^ (prow & 7)) * 16) + (kq & 1) * 8) = pk;
      }
      rs += __shfl_xor(rs, 16);
      rs += __shfl_xor(rs, 32);
      lacc[j] = lacc[j] * alpha + rs;
#pragma unroll
      for (int i = 0; i < 4; ++i) {
        o[i][j][0] *= alpha; o[i][j][1] *= alpha;
        o[i][j][2] *= alpha; o[i][j][3] *= alpha;
      }
    }

#pragma unroll
    for (int k0c = 0; k0c < 2; ++k0c) {
      bf16x8 pf[2];
#pragma unroll
      for (int j = 0; j < 2; ++j) {
        int prow = j * 16 + lr, c = k0c * 4 + kq;
        pf[j] = *(const bf16x8*)(pw + prow * 128 + ((c ^ (prow & 7)) * 16));
      }
#pragma unroll
      for (int i = 0; i < 4; ++i) {
        int d = i * 16 + lr, c = k0c * 4 + kq;
        bf16x8 vf = *(const bf16x8*)((char*)vsm[bi] + d * 128 +
                                     ((c ^ (d & 7)) * 16));
#pragma unroll
        for (int j = 0; j < 2; ++j)
          o[i][j] = __builtin_amdgcn_mfma_f32_16x16x32_bf16(vf, pf[j], o[i][j],
                                                            0, 0, 0);
      }
    }
  }

#pragma unroll
  for (int j = 0; j < 2; ++j) {
    float inv = 1.0f / lacc[j];
    int tok = q0 + wave * 32 + j * 16 + lr;
    bf16* op = attn + ((size_t)(b * N_ + tok)) * C_ + hh * HD_;
#pragma unroll
    for (int i = 0; i < 4; ++i) {
      bf16x4 pk = {(bf16)(o[i][j][0] * inv), (bf16)(o[i][j][1] * inv),
                   (bf16)(o[i][j][2] * inv), (bf16)(o[i][j][3] * inv)};
      *(bf16x4*)(op + i * 16 + kq * 4) = pk;
    }
  }
}

// ---------------------------------------------------------------------------
__global__ __launch_bounds__(256) void cast_all(
    const float* __restrict__ a, int na, const float* __restrict__ b, int nb,
    const float* __restrict__ c, int nc, const float* __restrict__ d,
    bf16* __restrict__ dst) {
  int i = (blockIdx.x * 256 + threadIdx.x) * 4;
  const float* src;
  int off;
  if (i < na) { src = a; off = i; }
  else if (i < na + nb) { src = b; off = i - na; }
  else if (i < na + nb + nc) { src = c; off = i - na - nb; }
  else { src = d; off = i - na - nb - nc; }
  float4 v = *(const float4*)(src + off);
  bf16x4 o = {(bf16)v.x, (bf16)v.y, (bf16)v.z, (bf16)v.w};
  *(bf16x4*)(dst + i) = o;
}

// depthwise 3x3 conv + bias + residual, fused transpose NCHW -> [B,N,C]
__global__ __launch_bounds__(256) void conv_pe_t(const float* __restrict__ x,
                                                 const float* __restrict__ cw,
                                                 const float* __restrict__ cb,
                                                 float* __restrict__ t0) {
  __shared__ float tile[32][33];
  const int h = blockIdx.x, ct = blockIdx.y, b = blockIdx.z;
  const int tid = threadIdx.x;
  const int w = tid & 31, cs = tid >> 5;
#pragma unroll
  for (int cc = cs; cc < 32; cc += 8) {
    int c = ct * 32 + cc;
    const float* xp = x + ((size_t)(b * C_ + c)) * 1024;
    const float* wp = cw + c * 9;
    float s = cb[c] + xp[h * 32 + w];
#pragma unroll
    for (int ky = 0; ky < 3; ++ky) {
      int hy = h + ky - 1;
      if ((unsigned)hy < 32u) {
#pragma unroll
        for (int kx = 0; kx < 3; ++kx) {
          int wx = w + kx - 1;
          if ((unsigned)wx < 32u) s += xp[hy * 32 + wx] * wp[ky * 3 + kx];
        }
      }
    }
    tile[cc][w] = s;
  }
  __syncthreads();
  const int cc = tid & 31;
#pragma unroll
  for (int wc = tid >> 5; wc < 32; wc += 8)
    t0[((size_t)(b * N_) + h * 32 + wc) * C_ + ct * 32 + cc] = tile[cc][wc];
}

// LayerNorm over C=768, fp32 in, bf16 out
__global__ __launch_bounds__(256) void ln_bf16(const float* __restrict__ t,
                                               const float* __restrict__ g,
                                               const float* __restrict__ be,
                                               bf16* __restrict__ out) {
  int row = blockIdx.x, tid = threadIdx.x;
  const float* p = t + (size_t)row * C_;
  float v0 = p[tid], v1 = p[tid + 256], v2 = p[tid + 512];
  __shared__ float rs[256], rq[256];
  rs[tid] = v0 + v1 + v2;
  rq[tid] = v0 * v0 + v1 * v1 + v2 * v2;
  __syncthreads();
  for (int off = 128; off; off >>= 1) {
    if (tid < off) {
      rs[tid] += rs[tid + off];
      rq[tid] += rq[tid + off];
    }
    __syncthreads();
  }
  float mu = rs[0] * (1.f / C_);
  float var = rq[0] * (1.f / C_) - mu * mu;
  float rstd = rsqrtf(var + 1e-5f);
  bf16* q = out + (size_t)row * C_;
  q[tid] = (bf16)((v0 - mu) * rstd * g[tid] + be[tid]);
  q[tid + 256] = (bf16)((v1 - mu) * rstd * g[tid + 256] + be[tid + 256]);
  q[tid + 512] = (bf16)((v2 - mu) * rstd * g[tid + 512] + be[tid + 512]);
}

// batched 2D transpose via LDS: out[b][cc][r] = in[b][r][cc]
__global__ __launch_bounds__(256) void transpose_f32(
    const float* __restrict__ in, float* __restrict__ out, int R, int Cc) {
  __shared__ float tile[32][33];
  int b = blockIdx.z;
  const float* ip = in + (size_t)b * R * Cc;
  float* op = out + (size_t)b * R * Cc;
  int c0 = blockIdx.x * 32, r0 = blockIdx.y * 32;
  int tx = threadIdx.x & 31, ty = threadIdx.x >> 5;
#pragma unroll
  for (int i = 0; i < 32; i += 8)
    tile[ty + i][tx] = ip[(size_t)(r0 + ty + i) * Cc + c0 + tx];
  __syncthreads();
#pragma unroll
  for (int i = 0; i < 32; i += 8)
    op[(size_t)(c0 + ty + i) * R + r0 + tx] = tile[tx][ty + i];
}

// ---------------------------------------------------------------------------
extern "C" void kernel_launch(void* const* d_in, const int* in_sizes, int n_in,
                              void* d_out, int out_size, void* d_ws,
                              size_t ws_size, hipStream_t stream) {
  (void)in_sizes; (void)n_in; (void)out_size; (void)ws_size;
  const float* x      = (const float*)d_in[0];
  const float* conv_w = (const float*)d_in[1];
  const float* conv_b = (const float*)d_in[2];
  const float* ln1_g  = (const float*)d_in[3];
  const float* ln1_b  = (const float*)d_in[4];
  const float* qkv_w  = (const float*)d_in[5];
  const float* proj_w = (const float*)d_in[6];
  const float* proj_b = (const float*)d_in[7];
  const float* ln2_g  = (const float*)d_in[8];
  const float* ln2_b  = (const float*)d_in[9];
  const float* fc1_w  = (const float*)d_in[10];
  const float* fc1_b  = (const float*)d_in[11];
  const float* fc2_w  = (const float*)d_in[12];
  const float* fc2_b  = (const float*)d_in[13];
  float* out = (float*)d_out;

  char* w = (char*)d_ws;
  auto carve = [&](size_t bytes) {
    char* p = w;
    w += (bytes + 255) & ~(size_t)255;
    return p;
  };
  bf16* hid   = (bf16*)carve((size_t)NTOK * HID_ * 2);
  float* t0   = (float*)carve((size_t)NTOK * C_ * 4);
  bf16* lnout = (bf16*)carve((size_t)NTOK * C_ * 2);
  bf16* wq    = (bf16*)carve((size_t)3 * C_ * C_ * 2);
  bf16* wp    = (bf16*)carve((size_t)C_ * C_ * 2);
  bf16* w1    = (bf16*)carve((size_t)HID_ * C_ * 2);
  bf16* w2    = (bf16*)carve((size_t)C_ * HID_ * 2);
  bf16* Qb    = (bf16*)carve((size_t)NHEADS * N_ * HD_ * 2);
  bf16* Kb    = (bf16*)carve((size_t)NHEADS * N_ * HD_ * 2);
  bf16* Vt    = (bf16*)carve((size_t)NHEADS * HD_ * N_ * 2);
  bf16* attn  = (bf16*)carve((size_t)NTOK * C_ * 2);

  const int na = 3 * C_ * C_, nb = C_ * C_, nc = HID_ * C_, nd = C_ * HID_;
  cast_all<<<(na + nb + nc + nd) / 1024, 256, 0, stream>>>(
      qkv_w, na, proj_w, nb, fc1_w, nc, fc2_w, wq);

  conv_pe_t<<<dim3(32, C_ / 32, B_), 256, 0, stream>>>(x, conv_w, conv_b, t0);

  ln_bf16<<<NTOK, 256, 0, stream>>>(t0, ln1_g, ln1_b, lnout);
  gemm_bt<0><<<dim3(3 * C_ / 128, NTOK / 128), 256, 0, stream>>>(
      lnout, wq, 768, 768, 768, Qb, Kb, Vt, nullptr, nullptr);

  flash_attn<<<dim3(N_ / 128, NHEADS), 256, 0, stream>>>(Qb, Kb, Vt, attn);

  gemm_bt<3><<<dim3(C_ / 128, NTOK / 128), 256, 0, stream>>>(
      attn, wp, 768, 768, 768, nullptr, nullptr, nullptr, t0, proj_b);
  ln_bf16<<<NTOK, 256, 0, stream>>>(t0, ln2_g, ln2_b, lnout);
  gemm_bt<4><<<dim3(HID_ / 128, NTOK / 128), 256, 0, stream>>>(
      lnout, w1, 768, 768, 768, hid, nullptr, nullptr, nullptr, fc1_b);
  gemm_bt<3><<<dim3(C_ / 128, NTOK / 128), 256, 0, stream>>>(
      hid, w2, 3072, 3072, 3072, nullptr, nullptr, nullptr, t0, fc2_b);

  transpose_f32<<<dim3(C_ / 32, N_ / 32, B_), 256, 0, stream>>>(t0, out, N_, C_);
}

// Round 6
// 409.902 us; speedup vs baseline: 1.7317x; 1.0380x over previous
//
#include <hip/hip_runtime.h>
#include <math.h>

// ---------------------------------------------------------------------------
// SABlock: x[B,C,H,W] -> depthwise3x3+res -> [B,N,C]: LN1 -> QKV -> flash-MHA
//          -> proj +res -> LN2 -> FC1 -> GELU -> FC2 -> +res -> [B,C,H,W]
// R6: proj/fc2 use 128x64 tiles (768 blocks = 3/CU, was 1.5/CU) + XCD-aware
// tile remap (A-stripe pinned to one XCD's L2). Keeps R5 wins: BK=64 swizzled
// LDS (0 conflicts), transposed-acc vector epilogues, fast exp2 GELU.
// ---------------------------------------------------------------------------

typedef __bf16 bf16;
typedef __attribute__((ext_vector_type(8))) __bf16 bf16x8;
typedef __attribute__((ext_vector_type(4))) __bf16 bf16x4;
typedef __attribute__((ext_vector_type(4))) float f32x4;

#define B_   8
#define C_   768
#define N_   1024
#define NH_  12
#define HD_  64
#define HID_ 3072
#define NTOK   (B_ * N_)     // 8192
#define NHEADS (B_ * NH_)    // 96
#define FA_C   0.1803368801111601f  // 0.125 * log2(e)

__device__ __forceinline__ void gload_lds16(const void* g, void* l) {
  __builtin_amdgcn_global_load_lds(
      (__attribute__((address_space(1))) void*)(void*)g,
      (__attribute__((address_space(3))) void*)l, 16, 0, 0);
}

__device__ __forceinline__ float gelu1(float x) {
  // tanh-form GELU via exp2; |err| well under bf16 noise (verified R4/R5)
  float u = 0.7978845608028654f * x * (1.0f + 0.044715f * x * x);
  float e = __builtin_amdgcn_exp2f(u * 2.885390081777927f);  // exp(2u)
  float th = 1.0f - 2.0f * __builtin_amdgcn_rcpf(e + 1.0f);
  return 0.5f * x * (1.0f + th);
}

// ---------------------------------------------------------------------------
// B^T GEMM, 128xBN tile, BK=64, 256 thr (2x2 waves; wave-tile 64 x BN/2).
// Transposed accumulators (operand-swapped MFMA): lane holds C[m][n..n+3],
//   m = m0+wm*64+i*16+lr,  n = n0+wn*(BN/2)+j*16+kq*4,  j < BN/32
// LDS: rows of 8 x 16B chunks, chunk slot = c ^ (row&7) -> 0 bank conflicts.
// REMAP: 1-D grid, xcd = bid&7 owns 8 consecutive m-stripes x all 12 n-tiles
//        (A-stripe L2 locality across the 8 non-coherent XCD L2s).
// EPI: 0 = QKV (Q,K vector stores; V via LDS-transpose bounce -> V^T rows)
//      3 = resid float4 RMW += v + bias      4 = GELU -> hid (bf16)
// ---------------------------------------------------------------------------
template <int BN, int EPI, bool REMAP>
__global__ __launch_bounds__(256) void gemm_bt(
    const bf16* __restrict__ A, const bf16* __restrict__ B, int K, int lda,
    int ldb, bf16* __restrict__ o0, bf16* __restrict__ o1,
    bf16* __restrict__ o2, float* __restrict__ resid,
    const float* __restrict__ bias) {
  constexpr int JJ = BN / 32;                      // j-tiles per wave
  __shared__ __align__(16) bf16 smem[(128 + BN) * 64];
  bf16* As = smem;
  bf16* Bs = smem + 128 * 64;

  const int tid = threadIdx.x;
  const int wave = tid >> 6, lane = tid & 63;
  const int wm = wave & 1, wn = wave >> 1;
  const int lr = lane & 15, kq = lane >> 4;
  const int sw = lr & 7;

  int m0, n0;
  if constexpr (REMAP) {
    const int bid = blockIdx.x;                    // 768 blocks, 12 n-tiles
    const int g = bid & 7, s = bid >> 3;           // s in [0,96)
    m0 = (g * 8 + s / 12) * 128;
    n0 = (s % 12) * BN;
  } else {
    m0 = blockIdx.y * 128;
    n0 = blockIdx.x * BN;
  }

  f32x4 acc[4][JJ];
#pragma unroll
  for (int i = 0; i < 4; i++)
#pragma unroll
    for (int j = 0; j < JJ; j++) acc[i][j] = (f32x4){0.f, 0.f, 0.f, 0.f};

  const bf16* Arow = A + (size_t)m0 * lda;
  const bf16* Brow = B + (size_t)n0 * ldb;

  for (int k0 = 0; k0 < K; k0 += 64) {
#pragma unroll
    for (int it = 0; it < 4; ++it) {               // A: 128 rows x 8 chunks
      int s = it * 256 + tid;
      int r = s >> 3, seg = (s & 7) ^ (r & 7);
      gload_lds16(Arow + (size_t)r * lda + k0 + seg * 8, (char*)As + s * 16);
    }
#pragma unroll
    for (int it = 0; it < BN / 32; ++it) {         // B: BN rows x 8 chunks
      int s = it * 256 + tid;
      int r = s >> 3, seg = (s & 7) ^ (r & 7);
      gload_lds16(Brow + (size_t)r * ldb + k0 + seg * 8, (char*)Bs + s * 16);
    }
    __syncthreads();

#pragma unroll
    for (int h = 0; h < 2; ++h) {
      bf16x8 af[4], bfr[JJ];
      const int c = h * 4 + kq;
#pragma unroll
      for (int i = 0; i < 4; i++) {
        int row = wm * 64 + i * 16 + lr;
        af[i] = *(const bf16x8*)((char*)As + (row * 8 + (c ^ sw)) * 16);
      }
#pragma unroll
      for (int j = 0; j < JJ; j++) {
        int row = wn * (BN / 2) + j * 16 + lr;
        bfr[j] = *(const bf16x8*)((char*)Bs + (row * 8 + (c ^ sw)) * 16);
      }
      // swapped operands -> transposed C/D layout
#pragma unroll
      for (int i = 0; i < 4; i++)
#pragma unroll
        for (int j = 0; j < JJ; j++)
          acc[i][j] = __builtin_amdgcn_mfma_f32_16x16x32_bf16(bfr[j], af[i],
                                                              acc[i][j], 0, 0, 0);
    }
    __syncthreads();
  }

  if constexpr (EPI == 0) {
    const int b = m0 >> 10, tok0 = m0 & (N_ - 1);
    if (n0 < 2 * C_) {
      // Q or K: vector bf16x4 stores, [head][tok][d]
      const int s = n0 >= C_ ? 1 : 0;
      bf16* dst = s ? o1 : o0;
#pragma unroll
      for (int i = 0; i < 4; i++) {
        const int m = m0 + wm * 64 + i * 16 + lr;
#pragma unroll
        for (int j = 0; j < JJ; j++) {
          const int rem = n0 - s * C_ + wn * (BN / 2) + j * 16 + kq * 4;
          const int h = rem >> 6, d = rem & 63;
          const f32x4 v = acc[i][j];
          bf16x4 pk = {(bf16)v[0], (bf16)v[1], (bf16)v[2], (bf16)v[3]};
          size_t head = (size_t)b * NH_ + h;
          *(bf16x4*)(dst + (head * N_ + (m & (N_ - 1))) * HD_ + d) = pk;
        }
      }
    } else {
      // V: bounce through LDS (32 KB tile, swizzled) -> coalesced V^T rows.
      bf16* tile = smem;
#pragma unroll
      for (int i = 0; i < 4; i++) {
        const int ml = wm * 64 + i * 16 + lr;
        const int mc = ml >> 3, mo = ml & 7;
#pragma unroll
        for (int j = 0; j < JJ; j++) {
          const f32x4 v = acc[i][j];
#pragma unroll
          for (int r = 0; r < 4; r++) {
            const int nl = wn * (BN / 2) + j * 16 + kq * 4 + r;
            *(bf16*)((char*)tile + nl * 256 + ((mc ^ (nl & 15)) * 16) + mo * 2) =
                (bf16)v[r];
          }
        }
      }
      __syncthreads();
      const int nl = tid >> 1, mh = (tid & 1) * 64;   // 128 rows x 2 halves
      const int vb = n0 - 2 * C_ + nl;                // channel within 768
      const size_t head = (size_t)b * NH_ + (vb >> 6);
      bf16* dst = o2 + (head * HD_ + (vb & 63)) * N_ + tok0 + mh;
#pragma unroll
      for (int c8 = 0; c8 < 8; ++c8) {
        const int c = (mh >> 3) + c8;
        bf16x8 val = *(const bf16x8*)((char*)tile + nl * 256 +
                                      ((c ^ (nl & 15)) * 16));
        *(bf16x8*)(dst + c8 * 8) = val;
      }
    }
  } else if constexpr (EPI == 3) {
#pragma unroll
    for (int j = 0; j < JJ; j++) {
      const int n = n0 + wn * (BN / 2) + j * 16 + kq * 4;
      const f32x4 bv = *(const f32x4*)(bias + n);
#pragma unroll
      for (int i = 0; i < 4; i++) {
        const int m = m0 + wm * 64 + i * 16 + lr;
        float* rp = resid + (size_t)m * C_ + n;
        f32x4 old = *(const f32x4*)rp;
        const f32x4 v = acc[i][j];
        f32x4 nw = {old[0] + v[0] + bv[0], old[1] + v[1] + bv[1],
                    old[2] + v[2] + bv[2], old[3] + v[3] + bv[3]};
        *(f32x4*)rp = nw;
      }
    }
  } else if constexpr (EPI == 4) {
#pragma unroll
    for (int j = 0; j < JJ; j++) {
      const int n = n0 + wn * (BN / 2) + j * 16 + kq * 4;
      const f32x4 bv = *(const f32x4*)(bias + n);
#pragma unroll
      for (int i = 0; i < 4; i++) {
        const int m = m0 + wm * 64 + i * 16 + lr;
        const f32x4 v = acc[i][j];
        bf16x4 pk = {(bf16)gelu1(v[0] + bv[0]), (bf16)gelu1(v[1] + bv[1]),
                     (bf16)gelu1(v[2] + bv[2]), (bf16)gelu1(v[3] + bv[3])};
        *(bf16x4*)(o0 + (size_t)m * HID_ + n) = pk;
      }
    }
  }
}

// ---------------------------------------------------------------------------
// Flash attention: grid (8 q-tiles, 96 heads) = 768 blocks, 256 thr.
// Wave owns 32 q-rows. 16 K-tiles of 64, double-buffered staging.
// ---------------------------------------------------------------------------
__global__ __launch_bounds__(256, 3) void flash_attn(
    const bf16* __restrict__ Qb, const bf16* __restrict__ Kb,
    const bf16* __restrict__ Vt, bf16* __restrict__ attn) {
  __shared__ __align__(16) bf16 ksm[2][64 * 64];
  __shared__ __align__(16) bf16 vsm[2][64 * 64];
  __shared__ __align__(16) bf16 psm[4][32 * 64];

  const int tid = threadIdx.x, wave = tid >> 6, lane = tid & 63;
  const int lr = lane & 15, kq = lane >> 4;
  const int head = blockIdx.y;
  const int b = head / NH_, hh = head - b * NH_;
  const int q0 = blockIdx.x * 128;
  const bf16* Qh = Qb + (size_t)head * (N_ * HD_);
  const bf16* Kh = Kb + (size_t)head * (N_ * HD_);
  const bf16* Vh = Vt + (size_t)head * (HD_ * N_);
  char* pw = (char*)&psm[wave][0];

  bf16x8 qf[2][2];
#pragma unroll
  for (int j = 0; j < 2; ++j)
#pragma unroll
    for (int kh = 0; kh < 2; ++kh)
      qf[j][kh] = *(const bf16x8*)(Qh +
                                   (size_t)(q0 + wave * 32 + j * 16 + lr) * HD_ +
                                   kh * 32 + kq * 8);

  f32x4 o[4][2];
#pragma unroll
  for (int i = 0; i < 4; i++)
#pragma unroll
    for (int j = 0; j < 2; j++) o[i][j] = (f32x4){0.f, 0.f, 0.f, 0.f};
  float mprev[2] = {-1e30f, -1e30f}, lacc[2] = {0.f, 0.f};

  auto stage = [&](int t, int bi) {
#pragma unroll
    for (int it = 0; it < 2; ++it) {
      int s = it * 256 + tid;
      int r = s >> 3, seg = (s & 7) ^ (r & 7);
      gload_lds16(Kh + (size_t)(t * 64 + r) * HD_ + seg * 8,
                  (char*)ksm[bi] + (it * 256 + wave * 64) * 16);
    }
#pragma unroll
    for (int it = 0; it < 2; ++it) {
      int s = it * 256 + tid;
      int r = s >> 3, seg = (s & 7) ^ (r & 7);
      gload_lds16(Vh + (size_t)r * N_ + t * 64 + seg * 8,
                  (char*)vsm[bi] + (it * 256 + wave * 64) * 16);
    }
  };

  stage(0, 0);

  for (int t = 0; t < 16; ++t) {
    const int bi = t & 1;
    __syncthreads();
    if (t < 15) stage(t + 1, bi ^ 1);

    f32x4 sacc[4][2];
#pragma unroll
    for (int i = 0; i < 4; ++i) {
#pragma unroll
      for (int j = 0; j < 2; ++j) sacc[i][j] = (f32x4){0.f, 0.f, 0.f, 0.f};
      int row = i * 16 + lr;
      bf16x8 kf0 = *(const bf16x8*)((char*)ksm[bi] + row * 128 +
                                    ((kq ^ (row & 7)) * 16));
      bf16x8 kf1 = *(const bf16x8*)((char*)ksm[bi] + row * 128 +
                                    (((4 + kq) ^ (row & 7)) * 16));
#pragma unroll
      for (int j = 0; j < 2; ++j) {
        sacc[i][j] = __builtin_amdgcn_mfma_f32_16x16x32_bf16(kf0, qf[j][0],
                                                             sacc[i][j], 0, 0, 0);
        sacc[i][j] = __builtin_amdgcn_mfma_f32_16x16x32_bf16(kf1, qf[j][1],
                                                             sacc[i][j], 0, 0, 0);
      }
    }

#pragma unroll
    for (int j = 0; j < 2; ++j) {
      float mx = -1e30f;
#pragma unroll
      for (int i = 0; i < 4; ++i)
#pragma unroll
        for (int r = 0; r < 4; ++r) mx = fmaxf(mx, sacc[i][j][r]);
      mx = fmaxf(mx, __shfl_xor(mx, 16));
      mx = fmaxf(mx, __shfl_xor(mx, 32));
      float mnew = fmaxf(mprev[j], mx);
      float alpha = __builtin_amdgcn_exp2f((mprev[j] - mnew) * FA_C);
      mprev[j] = mnew;
      float rs = 0.f;
      const int prow = j * 16 + lr;
#pragma unroll
      for (int i = 0; i < 4; ++i) {
        float p0 = __builtin_amdgcn_exp2f((sacc[i][j][0] - mnew) * FA_C);
        float p1 = __builtin_amdgcn_exp2f((sacc[i][j][1] - mnew) * FA_C);
        float p2 = __builtin_amdgcn_exp2f((sacc[i][j][2] - mnew) * FA_C);
        float p3 = __builtin_amdgcn_exp2f((sacc[i][j][3] - mnew) * FA_C);
        rs += (p0 + p1) + (p2 + p3);
        bf16x4 pk = {(bf16)p0, (bf16)p1, (bf16)p2, (bf16)p3};
        int c = i * 2 + (kq >> 1);
        *(bf16x4*)(pw + prow * 128 + ((c ^ (prow & 7)) * 16) + (kq & 1) * 8) = pk;
      }
      rs += __shfl_xor(rs, 16);
      rs += __shfl_xor(rs, 32);
      lacc[j] = lacc[j] * alpha + rs;
#pragma unroll
      for (int i = 0; i < 4; ++i) {
        o[i][j][0] *= alpha; o[i][j][1] *= alpha;
        o[i][j][2] *= alpha; o[i][j][3] *= alpha;
      }
    }

#pragma unroll
    for (int k0c = 0; k0c < 2; ++k0c) {
      bf16x8 pf[2];
#pragma unroll
      for (int j = 0; j < 2; ++j) {
        int prow = j * 16 + lr, c = k0c * 4 + kq;
        pf[j] = *(const bf16x8*)(pw + prow * 128 + ((c ^ (prow & 7)) * 16));
      }
#pragma unroll
      for (int i = 0; i < 4; ++i) {
        int d = i * 16 + lr, c = k0c * 4 + kq;
        bf16x8 vf = *(const bf16x8*)((char*)vsm[bi] + d * 128 +
                                     ((c ^ (d & 7)) * 16));
#pragma unroll
        for (int j = 0; j < 2; ++j)
          o[i][j] = __builtin_amdgcn_mfma_f32_16x16x32_bf16(vf, pf[j], o[i][j],
                                                            0, 0, 0);
      }
    }
  }

#pragma unroll
  for (int j = 0; j < 2; ++j) {
    float inv = 1.0f / lacc[j];
    int tok = q0 + wave * 32 + j * 16 + lr;
    bf16* op = attn + ((size_t)(b * N_ + tok)) * C_ + hh * HD_;
#pragma unroll
    for (int i = 0; i < 4; ++i) {
      bf16x4 pk = {(bf16)(o[i][j][0] * inv), (bf16)(o[i][j][1] * inv),
                   (bf16)(o[i][j][2] * inv), (bf16)(o[i][j][3] * inv)};
      *(bf16x4*)(op + i * 16 + kq * 4) = pk;
    }
  }
}

// ---------------------------------------------------------------------------
__global__ __launch_bounds__(256) void cast_all(
    const float* __restrict__ a, int na, const float* __restrict__ b, int nb,
    const float* __restrict__ c, int nc, const float* __restrict__ d,
    bf16* __restrict__ dst) {
  int i = (blockIdx.x * 256 + threadIdx.x) * 4;
  const float* src;
  int off;
  if (i < na) { src = a; off = i; }
  else if (i < na + nb) { src = b; off = i - na; }
  else if (i < na + nb + nc) { src = c; off = i - na - nb; }
  else { src = d; off = i - na - nb - nc; }
  float4 v = *(const float4*)(src + off);
  bf16x4 o = {(bf16)v.x, (bf16)v.y, (bf16)v.z, (bf16)v.w};
  *(bf16x4*)(dst + i) = o;
}

// depthwise 3x3 conv + bias + residual, fused transpose NCHW -> [B,N,C]
__global__ __launch_bounds__(256) void conv_pe_t(const float* __restrict__ x,
                                                 const float* __restrict__ cw,
                                                 const float* __restrict__ cb,
                                                 float* __restrict__ t0) {
  __shared__ float tile[32][33];
  const int h = blockIdx.x, ct = blockIdx.y, b = blockIdx.z;
  const int tid = threadIdx.x;
  const int w = tid & 31, cs = tid >> 5;
#pragma unroll
  for (int cc = cs; cc < 32; cc += 8) {
    int c = ct * 32 + cc;
    const float* xp = x + ((size_t)(b * C_ + c)) * 1024;
    const float* wp = cw + c * 9;
    float s = cb[c] + xp[h * 32 + w];
#pragma unroll
    for (int ky = 0; ky < 3; ++ky) {
      int hy = h + ky - 1;
      if ((unsigned)hy < 32u) {
#pragma unroll
        for (int kx = 0; kx < 3; ++kx) {
          int wx = w + kx - 1;
          if ((unsigned)wx < 32u) s += xp[hy * 32 + wx] * wp[ky * 3 + kx];
        }
      }
    }
    tile[cc][w] = s;
  }
  __syncthreads();
  const int cc = tid & 31;
#pragma unroll
  for (int wc = tid >> 5; wc < 32; wc += 8)
    t0[((size_t)(b * N_) + h * 32 + wc) * C_ + ct * 32 + cc] = tile[cc][wc];
}

// LayerNorm over C=768, fp32 in, bf16 out
__global__ __launch_bounds__(256) void ln_bf16(const float* __restrict__ t,
                                               const float* __restrict__ g,
                                               const float* __restrict__ be,
                                               bf16* __restrict__ out) {
  int row = blockIdx.x, tid = threadIdx.x;
  const float* p = t + (size_t)row * C_;
  float v0 = p[tid], v1 = p[tid + 256], v2 = p[tid + 512];
  __shared__ float rs[256], rq[256];
  rs[tid] = v0 + v1 + v2;
  rq[tid] = v0 * v0 + v1 * v1 + v2 * v2;
  __syncthreads();
  for (int off = 128; off; off >>= 1) {
    if (tid < off) {
      rs[tid] += rs[tid + off];
      rq[tid] += rq[tid + off];
    }
    __syncthreads();
  }
  float mu = rs[0] * (1.f / C_);
  float var = rq[0] * (1.f / C_) - mu * mu;
  float rstd = rsqrtf(var + 1e-5f);
  bf16* q = out + (size_t)row * C_;
  q[tid] = (bf16)((v0 - mu) * rstd * g[tid] + be[tid]);
  q[tid + 256] = (bf16)((v1 - mu) * rstd * g[tid + 256] + be[tid + 256]);
  q[tid + 512] = (bf16)((v2 - mu) * rstd * g[tid + 512] + be[tid + 512]);
}

// batched 2D transpose via LDS: out[b][cc][r] = in[b][r][cc]
__global__ __launch_bounds__(256) void transpose_f32(
    const float* __restrict__ in, float* __restrict__ out, int R, int Cc) {
  __shared__ float tile[32][33];
  int b = blockIdx.z;
  const float* ip = in + (size_t)b * R * Cc;
  float* op = out + (size_t)b * R * Cc;
  int c0 = blockIdx.x * 32, r0 = blockIdx.y * 32;
  int tx = threadIdx.x & 31, ty = threadIdx.x >> 5;
#pragma unroll
  for (int i = 0; i < 32; i += 8)
    tile[ty + i][tx] = ip[(size_t)(r0 + ty + i) * Cc + c0 + tx];
  __syncthreads();
#pragma unroll
  for (int i = 0; i < 32; i += 8)
    op[(size_t)(c0 + ty + i) * R + r0 + tx] = tile[tx][ty + i];
}

// ---------------------------------------------------------------------------
extern "C" void kernel_launch(void* const* d_in, const int* in_sizes, int n_in,
                              void* d_out, int out_size, void* d_ws,
                              size_t ws_size, hipStream_t stream) {
  (void)in_sizes; (void)n_in; (void)out_size; (void)ws_size;
  const float* x      = (const float*)d_in[0];
  const float* conv_w = (const float*)d_in[1];
  const float* conv_b = (const float*)d_in[2];
  const float* ln1_g  = (const float*)d_in[3];
  const float* ln1_b  = (const float*)d_in[4];
  const float* qkv_w  = (const float*)d_in[5];
  const float* proj_w = (const float*)d_in[6];
  const float* proj_b = (const float*)d_in[7];
  const float* ln2_g  = (const float*)d_in[8];
  const float* ln2_b  = (const float*)d_in[9];
  const float* fc1_w  = (const float*)d_in[10];
  const float* fc1_b  = (const float*)d_in[11];
  const float* fc2_w  = (const float*)d_in[12];
  const float* fc2_b  = (const float*)d_in[13];
  float* out = (float*)d_out;

  char* w = (char*)d_ws;
  auto carve = [&](size_t bytes) {
    char* p = w;
    w += (bytes + 255) & ~(size_t)255;
    return p;
  };
  bf16* hid   = (bf16*)carve((size_t)NTOK * HID_ * 2);
  float* t0   = (float*)carve((size_t)NTOK * C_ * 4);
  bf16* lnout = (bf16*)carve((size_t)NTOK * C_ * 2);
  bf16* wq    = (bf16*)carve((size_t)3 * C_ * C_ * 2);
  bf16* wp    = (bf16*)carve((size_t)C_ * C_ * 2);
  bf16* w1    = (bf16*)carve((size_t)HID_ * C_ * 2);
  bf16* w2    = (bf16*)carve((size_t)C_ * HID_ * 2);
  bf16* Qb    = (bf16*)carve((size_t)NHEADS * N_ * HD_ * 2);
  bf16* Kb    = (bf16*)carve((size_t)NHEADS * N_ * HD_ * 2);
  bf16* Vt    = (bf16*)carve((size_t)NHEADS * HD_ * N_ * 2);
  bf16* attn  = (bf16*)carve((size_t)NTOK * C_ * 2);

  const int na = 3 * C_ * C_, nb = C_ * C_, nc = HID_ * C_, nd = C_ * HID_;
  cast_all<<<(na + nb + nc + nd) / 1024, 256, 0, stream>>>(
      qkv_w, na, proj_w, nb, fc1_w, nc, fc2_w, wq);

  conv_pe_t<<<dim3(32, C_ / 32, B_), 256, 0, stream>>>(x, conv_w, conv_b, t0);

  ln_bf16<<<NTOK, 256, 0, stream>>>(t0, ln1_g, ln1_b, lnout);
  gemm_bt<128, 0, false><<<dim3(3 * C_ / 128, NTOK / 128), 256, 0, stream>>>(
      lnout, wq, 768, 768, 768, Qb, Kb, Vt, nullptr, nullptr);

  flash_attn<<<dim3(N_ / 128, NHEADS), 256, 0, stream>>>(Qb, Kb, Vt, attn);

  // proj / fc2: 128x64 tiles, 768 blocks (3/CU), XCD-aware A-stripe remap
  gemm_bt<64, 3, true><<<768, 256, 0, stream>>>(
      attn, wp, 768, 768, 768, nullptr, nullptr, nullptr, t0, proj_b);
  ln_bf16<<<NTOK, 256, 0, stream>>>(t0, ln2_g, ln2_b, lnout);
  gemm_bt<128, 4, false><<<dim3(HID_ / 128, NTOK / 128), 256, 0, stream>>>(
      lnout, w1, 768, 768, 768, hid, nullptr, nullptr, nullptr, fc1_b);
  gemm_bt<64, 3, true><<<768, 256, 0, stream>>>(
      hid, w2, 3072, 3072, 3072, nullptr, nullptr, nullptr, t0, fc2_b);

  transpose_f32<<<dim3(C_ / 32, N_ / 32, B_), 256, 0, stream>>>(t0, out, N_, C_);
}

// Round 7
// 394.424 us; speedup vs baseline: 1.7996x; 1.0392x over previous
//
#include <hip/hip_runtime.h>
#include <math.h>

// ---------------------------------------------------------------------------
// SABlock: x[B,C,H,W] -> depthwise3x3+res -> [B,N,C]: LN1 -> QKV -> flash-MHA
//          -> proj +res -> LN2 -> FC1 -> GELU -> FC2 -> +res -> [B,C,H,W]
// R7: staging-pointer hoisting (VALU cut), XCD remap on ALL gemms, fc2
// epilogue writes NCHW output directly (LDS f32 bounce) -- transpose kernel
// gone. Keeps: BK=64 swizzled LDS (0 conflicts), transposed-acc vector
// epilogues, fast exp2 GELU, double-buffered flash attention.
// ---------------------------------------------------------------------------

typedef __bf16 bf16;
typedef __attribute__((ext_vector_type(8))) __bf16 bf16x8;
typedef __attribute__((ext_vector_type(4))) __bf16 bf16x4;
typedef __attribute__((ext_vector_type(4))) float f32x4;

#define B_   8
#define C_   768
#define N_   1024
#define NH_  12
#define HD_  64
#define HID_ 3072
#define NTOK   (B_ * N_)     // 8192
#define NHEADS (B_ * NH_)    // 96
#define FA_C   0.1803368801111601f  // 0.125 * log2(e)

__device__ __forceinline__ void gload_lds16(const void* g, void* l) {
  __builtin_amdgcn_global_load_lds(
      (__attribute__((address_space(1))) void*)(void*)g,
      (__attribute__((address_space(3))) void*)l, 16, 0, 0);
}

__device__ __forceinline__ float gelu1(float x) {
  // tanh-form GELU via exp2; |err| well under bf16 noise (verified R4/R5)
  float u = 0.7978845608028654f * x * (1.0f + 0.044715f * x * x);
  float e = __builtin_amdgcn_exp2f(u * 2.885390081777927f);  // exp(2u)
  float th = 1.0f - 2.0f * __builtin_amdgcn_rcpf(e + 1.0f);
  return 0.5f * x * (1.0f + th);
}

// ---------------------------------------------------------------------------
// B^T GEMM, 128xBN tile, BK=64, 256 thr (2x2 waves; wave-tile 64 x BN/2).
// Transposed accumulators (operand-swapped MFMA): lane holds C[m][n..n+3],
//   m = m0+wm*64+i*16+lr,  n = n0+wn*(BN/2)+j*16+kq*4,  j < BN/32
// LDS: rows of 8 x 16B chunks, chunk slot = c ^ (row&7) -> 0 bank conflicts.
// REMAP: 1-D grid; xcd g = bid&7 owns m-stripes [8g,8g+8) x all ntiles
//        n-tiles (A-stripe pinned to one XCD's L2).
// Staging pointers hoisted: per-thread chunk addrs computed once, += 64/iter.
// EPI: 0 = QKV (Q,K vector stores; V via LDS bounce -> V^T rows)
//      3 = resid float4 RMW += v + bias      4 = GELU -> hid (bf16)
//      5 = out_nchw = resid + v + bias (LDS f32 bounce, coalesced rows)
// ---------------------------------------------------------------------------
template <int BN, int EPI, bool REMAP>
__global__ __launch_bounds__(256) void gemm_bt(
    const bf16* __restrict__ A, const bf16* __restrict__ B, int K, int lda,
    int ldb, int ntiles, bf16* __restrict__ o0, bf16* __restrict__ o1,
    bf16* __restrict__ o2, float* __restrict__ resid,
    const float* __restrict__ bias, float* __restrict__ outp) {
  constexpr int JJ = BN / 32;                      // j-tiles per wave
  constexpr int BCH = BN / 32;                     // B staging chunks/thread
  constexpr int STAGE_B = (128 + BN) * 64 * 2;
  constexpr int EXTRA_B = (EPI == 5) ? 64 * 132 * 4 : (EPI == 0 ? 128 * 256 : 0);
  constexpr int SMEM_B = STAGE_B > EXTRA_B ? STAGE_B : EXTRA_B;
  __shared__ __align__(16) char smemraw[SMEM_B];
  bf16* As = (bf16*)smemraw;
  bf16* Bs = As + 128 * 64;

  const int tid = threadIdx.x;
  const int wave = tid >> 6, lane = tid & 63;
  const int wm = wave & 1, wn = wave >> 1;
  const int lr = lane & 15, kq = lane >> 4;
  const int sw = lr & 7;

  int m0, n0;
  if constexpr (REMAP) {
    const int bid = blockIdx.x;
    const int g = bid & 7, s = bid >> 3;
    const int ms = s / ntiles;
    m0 = (g * 8 + ms) * 128;
    n0 = (s - ms * ntiles) * BN;
  } else {
    m0 = blockIdx.y * 128;
    n0 = blockIdx.x * BN;
  }

  f32x4 acc[4][JJ];
#pragma unroll
  for (int i = 0; i < 4; i++)
#pragma unroll
    for (int j = 0; j < JJ; j++) acc[i][j] = (f32x4){0.f, 0.f, 0.f, 0.f};

  // hoisted per-thread staging addresses (advance by 64 elems per K-iter)
  const bf16* ap[4];
  const bf16* bp[BCH];
  {
    const bf16* Arow = A + (size_t)m0 * lda;
    const bf16* Brow = B + (size_t)n0 * ldb;
#pragma unroll
    for (int it = 0; it < 4; ++it) {
      int s = it * 256 + tid;
      int r = s >> 3, seg = (s & 7) ^ (r & 7);
      ap[it] = Arow + (size_t)r * lda + seg * 8;
    }
#pragma unroll
    for (int it = 0; it < BCH; ++it) {
      int s = it * 256 + tid;
      int r = s >> 3, seg = (s & 7) ^ (r & 7);
      bp[it] = Brow + (size_t)r * ldb + seg * 8;
    }
  }

  for (int k0 = 0; k0 < K; k0 += 64) {
#pragma unroll
    for (int it = 0; it < 4; ++it) {
      gload_lds16(ap[it], (char*)As + (it * 256 + tid) * 16);
      ap[it] += 64;
    }
#pragma unroll
    for (int it = 0; it < BCH; ++it) {
      gload_lds16(bp[it], (char*)Bs + (it * 256 + tid) * 16);
      bp[it] += 64;
    }
    __syncthreads();

#pragma unroll
    for (int h = 0; h < 2; ++h) {
      bf16x8 af[4], bfr[JJ];
      const int c = h * 4 + kq;
#pragma unroll
      for (int i = 0; i < 4; i++) {
        int row = wm * 64 + i * 16 + lr;
        af[i] = *(const bf16x8*)((char*)As + (row * 8 + (c ^ sw)) * 16);
      }
#pragma unroll
      for (int j = 0; j < JJ; j++) {
        int row = wn * (BN / 2) + j * 16 + lr;
        bfr[j] = *(const bf16x8*)((char*)Bs + (row * 8 + (c ^ sw)) * 16);
      }
      // swapped operands -> transposed C/D layout
#pragma unroll
      for (int i = 0; i < 4; i++)
#pragma unroll
        for (int j = 0; j < JJ; j++)
          acc[i][j] = __builtin_amdgcn_mfma_f32_16x16x32_bf16(bfr[j], af[i],
                                                              acc[i][j], 0, 0, 0);
    }
    __syncthreads();
  }

  if constexpr (EPI == 0) {
    const int b = m0 >> 10, tok0 = m0 & (N_ - 1);
    if (n0 < 2 * C_) {
      // Q or K: vector bf16x4 stores, [head][tok][d]
      const int s = n0 >= C_ ? 1 : 0;
      bf16* dst = s ? o1 : o0;
#pragma unroll
      for (int i = 0; i < 4; i++) {
        const int m = m0 + wm * 64 + i * 16 + lr;
#pragma unroll
        for (int j = 0; j < JJ; j++) {
          const int rem = n0 - s * C_ + wn * (BN / 2) + j * 16 + kq * 4;
          const int h = rem >> 6, d = rem & 63;
          const f32x4 v = acc[i][j];
          bf16x4 pk = {(bf16)v[0], (bf16)v[1], (bf16)v[2], (bf16)v[3]};
          size_t head = (size_t)b * NH_ + h;
          *(bf16x4*)(dst + (head * N_ + (m & (N_ - 1))) * HD_ + d) = pk;
        }
      }
    } else {
      // V: bounce through LDS (swizzled) -> coalesced V^T rows
      bf16* tile = (bf16*)smemraw;
#pragma unroll
      for (int i = 0; i < 4; i++) {
        const int ml = wm * 64 + i * 16 + lr;
        const int mc = ml >> 3, mo = ml & 7;
#pragma unroll
        for (int j = 0; j < JJ; j++) {
          const f32x4 v = acc[i][j];
#pragma unroll
          for (int r = 0; r < 4; r++) {
            const int nl = wn * (BN / 2) + j * 16 + kq * 4 + r;
            *(bf16*)((char*)tile + nl * 256 + ((mc ^ (nl & 15)) * 16) + mo * 2) =
                (bf16)v[r];
          }
        }
      }
      __syncthreads();
      const int nl = tid >> 1, mh = (tid & 1) * 64;   // 128 rows x 2 halves
      const int vb = n0 - 2 * C_ + nl;                // channel within 768
      const size_t head = (size_t)b * NH_ + (vb >> 6);
      bf16* dst = o2 + (head * HD_ + (vb & 63)) * N_ + tok0 + mh;
#pragma unroll
      for (int c8 = 0; c8 < 8; ++c8) {
        const int c = (mh >> 3) + c8;
        bf16x8 val = *(const bf16x8*)((char*)tile + nl * 256 +
                                      ((c ^ (nl & 15)) * 16));
        *(bf16x8*)(dst + c8 * 8) = val;
      }
    }
  } else if constexpr (EPI == 3) {
#pragma unroll
    for (int j = 0; j < JJ; j++) {
      const int n = n0 + wn * (BN / 2) + j * 16 + kq * 4;
      const f32x4 bv = *(const f32x4*)(bias + n);
#pragma unroll
      for (int i = 0; i < 4; i++) {
        const int m = m0 + wm * 64 + i * 16 + lr;
        float* rp = resid + (size_t)m * C_ + n;
        f32x4 old = *(const f32x4*)rp;
        const f32x4 v = acc[i][j];
        f32x4 nw = {old[0] + v[0] + bv[0], old[1] + v[1] + bv[1],
                    old[2] + v[2] + bv[2], old[3] + v[3] + bv[3]};
        *(f32x4*)rp = nw;
      }
    }
  } else if constexpr (EPI == 4) {
#pragma unroll
    for (int j = 0; j < JJ; j++) {
      const int n = n0 + wn * (BN / 2) + j * 16 + kq * 4;
      const f32x4 bv = *(const f32x4*)(bias + n);
#pragma unroll
      for (int i = 0; i < 4; i++) {
        const int m = m0 + wm * 64 + i * 16 + lr;
        const f32x4 v = acc[i][j];
        bf16x4 pk = {(bf16)gelu1(v[0] + bv[0]), (bf16)gelu1(v[1] + bv[1]),
                     (bf16)gelu1(v[2] + bv[2]), (bf16)gelu1(v[3] + bv[3])};
        *(bf16x4*)(o0 + (size_t)m * HID_ + n) = pk;
      }
    }
  } else if constexpr (EPI == 5) {
    // final = resid + v + bias, transposed to NCHW via LDS f32 tile [64][132]
    float* tile = (float*)smemraw;
    const int b = m0 >> 10, tok0 = m0 & (N_ - 1);
#pragma unroll
    for (int j = 0; j < JJ; j++) {
      const int nl0 = wn * (BN / 2) + j * 16 + kq * 4;
      const int n = n0 + nl0;
      const f32x4 bv = *(const f32x4*)(bias + n);
#pragma unroll
      for (int i = 0; i < 4; i++) {
        const int ml = wm * 64 + i * 16 + lr;
        const float* rp = resid + (size_t)(m0 + ml) * C_ + n;
        f32x4 old = *(const f32x4*)rp;
        const f32x4 v = acc[i][j];
#pragma unroll
        for (int r = 0; r < 4; r++)
          tile[(nl0 + r) * 132 + ml] = old[r] + v[r] + bv[r];
      }
    }
    __syncthreads();
    const int nl = tid & 63, mc = tid >> 6;      // 64 rows x 4 m-chunks of 32
    float* dst = outp + ((size_t)(b * C_ + n0 + nl)) * N_ + tok0 + mc * 32;
    const float* src = tile + nl * 132 + mc * 32;
#pragma unroll
    for (int q = 0; q < 8; ++q)
      *(f32x4*)(dst + q * 4) = *(const f32x4*)(src + q * 4);
  }
}

// ---------------------------------------------------------------------------
// Flash attention: grid (8 q-tiles, 96 heads) = 768 blocks, 256 thr.
// Wave owns 32 q-rows. 16 K-tiles of 64, double-buffered staging.
// ---------------------------------------------------------------------------
__global__ __launch_bounds__(256, 3) void flash_attn(
    const bf16* __restrict__ Qb, const bf16* __restrict__ Kb,
    const bf16* __restrict__ Vt, bf16* __restrict__ attn) {
  __shared__ __align__(16) bf16 ksm[2][64 * 64];
  __shared__ __align__(16) bf16 vsm[2][64 * 64];
  __shared__ __align__(16) bf16 psm[4][32 * 64];

  const int tid = threadIdx.x, wave = tid >> 6, lane = tid & 63;
  const int lr = lane & 15, kq = lane >> 4;
  const int head = blockIdx.y;
  const int b = head / NH_, hh = head - b * NH_;
  const int q0 = blockIdx.x * 128;
  const bf16* Qh = Qb + (size_t)head * (N_ * HD_);
  const bf16* Kh = Kb + (size_t)head * (N_ * HD_);
  const bf16* Vh = Vt + (size_t)head * (HD_ * N_);
  char* pw = (char*)&psm[wave][0];

  bf16x8 qf[2][2];
#pragma unroll
  for (int j = 0; j < 2; ++j)
#pragma unroll
    for (int kh = 0; kh < 2; ++kh)
      qf[j][kh] = *(const bf16x8*)(Qh +
                                   (size_t)(q0 + wave * 32 + j * 16 + lr) * HD_ +
                                   kh * 32 + kq * 8);

  f32x4 o[4][2];
#pragma unroll
  for (int i = 0; i < 4; i++)
#pragma unroll
    for (int j = 0; j < 2; j++) o[i][j] = (f32x4){0.f, 0.f, 0.f, 0.f};
  float mprev[2] = {-1e30f, -1e30f}, lacc[2] = {0.f, 0.f};

  auto stage = [&](int t, int bi) {
#pragma unroll
    for (int it = 0; it < 2; ++it) {
      int s = it * 256 + tid;
      int r = s >> 3, seg = (s & 7) ^ (r & 7);
      gload_lds16(Kh + (size_t)(t * 64 + r) * HD_ + seg * 8,
                  (char*)ksm[bi] + (it * 256 + wave * 64) * 16);
    }
#pragma unroll
    for (int it = 0; it < 2; ++it) {
      int s = it * 256 + tid;
      int r = s >> 3, seg = (s & 7) ^ (r & 7);
      gload_lds16(Vh + (size_t)r * N_ + t * 64 + seg * 8,
                  (char*)vsm[bi] + (it * 256 + wave * 64) * 16);
    }
  };

  stage(0, 0);

  for (int t = 0; t < 16; ++t) {
    const int bi = t & 1;
    __syncthreads();
    if (t < 15) stage(t + 1, bi ^ 1);

    f32x4 sacc[4][2];
#pragma unroll
    for (int i = 0; i < 4; ++i) {
#pragma unroll
      for (int j = 0; j < 2; ++j) sacc[i][j] = (f32x4){0.f, 0.f, 0.f, 0.f};
      int row = i * 16 + lr;
      bf16x8 kf0 = *(const bf16x8*)((char*)ksm[bi] + row * 128 +
                                    ((kq ^ (row & 7)) * 16));
      bf16x8 kf1 = *(const bf16x8*)((char*)ksm[bi] + row * 128 +
                                    (((4 + kq) ^ (row & 7)) * 16));
#pragma unroll
      for (int j = 0; j < 2; ++j) {
        sacc[i][j] = __builtin_amdgcn_mfma_f32_16x16x32_bf16(kf0, qf[j][0],
                                                             sacc[i][j], 0, 0, 0);
        sacc[i][j] = __builtin_amdgcn_mfma_f32_16x16x32_bf16(kf1, qf[j][1],
                                                             sacc[i][j], 0, 0, 0);
      }
    }

#pragma unroll
    for (int j = 0; j < 2; ++j) {
      float mx = -1e30f;
#pragma unroll
      for (int i = 0; i < 4; ++i)
#pragma unroll
        for (int r = 0; r < 4; ++r) mx = fmaxf(mx, sacc[i][j][r]);
      mx = fmaxf(mx, __shfl_xor(mx, 16));
      mx = fmaxf(mx, __shfl_xor(mx, 32));
      float mnew = fmaxf(mprev[j], mx);
      float alpha = __builtin_amdgcn_exp2f((mprev[j] - mnew) * FA_C);
      mprev[j] = mnew;
      float rs = 0.f;
      const int prow = j * 16 + lr;
#pragma unroll
      for (int i = 0; i < 4; ++i) {
        float p0 = __builtin_amdgcn_exp2f((sacc[i][j][0] - mnew) * FA_C);
        float p1 = __builtin_amdgcn_exp2f((sacc[i][j][1] - mnew) * FA_C);
        float p2 = __builtin_amdgcn_exp2f((sacc[i][j][2] - mnew) * FA_C);
        float p3 = __builtin_amdgcn_exp2f((sacc[i][j][3] - mnew) * FA_C);
        rs += (p0 + p1) + (p2 + p3);
        bf16x4 pk = {(bf16)p0, (bf16)p1, (bf16)p2, (bf16)p3};
        int c = i * 2 + (kq >> 1);
        *(bf16x4*)(pw + prow * 128 + ((c ^ (prow & 7)) * 16) + (kq & 1) * 8) = pk;
      }
      rs += __shfl_xor(rs, 16);
      rs += __shfl_xor(rs, 32);
      lacc[j] = lacc[j] * alpha + rs;
#pragma unroll
      for (int i = 0; i < 4; ++i) {
        o[i][j][0] *= alpha; o[i][j][1] *= alpha;
        o[i][j][2] *= alpha; o[i][j][3] *= alpha;
      }
    }

#pragma unroll
    for (int k0c = 0; k0c < 2; ++k0c) {
      bf16x8 pf[2];
#pragma unroll
      for (int j = 0; j < 2; ++j) {
        int prow = j * 16 + lr, c = k0c * 4 + kq;
        pf[j] = *(const bf16x8*)(pw + prow * 128 + ((c ^ (prow & 7)) * 16));
      }
#pragma unroll
      for (int i = 0; i < 4; ++i) {
        int d = i * 16 + lr, c = k0c * 4 + kq;
        bf16x8 vf = *(const bf16x8*)((char*)vsm[bi] + d * 128 +
                                     ((c ^ (d & 7)) * 16));
#pragma unroll
        for (int j = 0; j < 2; ++j)
          o[i][j] = __builtin_amdgcn_mfma_f32_16x16x32_bf16(vf, pf[j], o[i][j],
                                                            0, 0, 0);
      }
    }
  }

#pragma unroll
  for (int j = 0; j < 2; ++j) {
    float inv = 1.0f / lacc[j];
    int tok = q0 + wave * 32 + j * 16 + lr;
    bf16* op = attn + ((size_t)(b * N_ + tok)) * C_ + hh * HD_;
#pragma unroll
    for (int i = 0; i < 4; ++i) {
      bf16x4 pk = {(bf16)(o[i][j][0] * inv), (bf16)(o[i][j][1] * inv),
                   (bf16)(o[i][j][2] * inv), (bf16)(o[i][j][3] * inv)};
      *(bf16x4*)(op + i * 16 + kq * 4) = pk;
    }
  }
}

// ---------------------------------------------------------------------------
__global__ __launch_bounds__(256) void cast_all(
    const float* __restrict__ a, int na, const float* __restrict__ b, int nb,
    const float* __restrict__ c, int nc, const float* __restrict__ d,
    bf16* __restrict__ dst) {
  int i = (blockIdx.x * 256 + threadIdx.x) * 4;
  const float* src;
  int off;
  if (i < na) { src = a; off = i; }
  else if (i < na + nb) { src = b; off = i - na; }
  else if (i < na + nb + nc) { src = c; off = i - na - nb; }
  else { src = d; off = i - na - nb - nc; }
  float4 v = *(const float4*)(src + off);
  bf16x4 o = {(bf16)v.x, (bf16)v.y, (bf16)v.z, (bf16)v.w};
  *(bf16x4*)(dst + i) = o;
}

// depthwise 3x3 conv + bias + residual, fused transpose NCHW -> [B,N,C]
__global__ __launch_bounds__(256) void conv_pe_t(const float* __restrict__ x,
                                                 const float* __restrict__ cw,
                                                 const float* __restrict__ cb,
                                                 float* __restrict__ t0) {
  __shared__ float tile[32][33];
  const int h = blockIdx.x, ct = blockIdx.y, b = blockIdx.z;
  const int tid = threadIdx.x;
  const int w = tid & 31, cs = tid >> 5;
#pragma unroll
  for (int cc = cs; cc < 32; cc += 8) {
    int c = ct * 32 + cc;
    const float* xp = x + ((size_t)(b * C_ + c)) * 1024;
    const float* wp = cw + c * 9;
    float s = cb[c] + xp[h * 32 + w];
#pragma unroll
    for (int ky = 0; ky < 3; ++ky) {
      int hy = h + ky - 1;
      if ((unsigned)hy < 32u) {
#pragma unroll
        for (int kx = 0; kx < 3; ++kx) {
          int wx = w + kx - 1;
          if ((unsigned)wx < 32u) s += xp[hy * 32 + wx] * wp[ky * 3 + kx];
        }
      }
    }
    tile[cc][w] = s;
  }
  __syncthreads();
  const int cc = tid & 31;
#pragma unroll
  for (int wc = tid >> 5; wc < 32; wc += 8)
    t0[((size_t)(b * N_) + h * 32 + wc) * C_ + ct * 32 + cc] = tile[cc][wc];
}

// LayerNorm over C=768, fp32 in, bf16 out
__global__ __launch_bounds__(256) void ln_bf16(const float* __restrict__ t,
                                               const float* __restrict__ g,
                                               const float* __restrict__ be,
                                               bf16* __restrict__ out) {
  int row = blockIdx.x, tid = threadIdx.x;
  const float* p = t + (size_t)row * C_;
  float v0 = p[tid], v1 = p[tid + 256], v2 = p[tid + 512];
  __shared__ float rs[256], rq[256];
  rs[tid] = v0 + v1 + v2;
  rq[tid] = v0 * v0 + v1 * v1 + v2 * v2;
  __syncthreads();
  for (int off = 128; off; off >>= 1) {
    if (tid < off) {
      rs[tid] += rs[tid + off];
      rq[tid] += rq[tid + off];
    }
    __syncthreads();
  }
  float mu = rs[0] * (1.f / C_);
  float var = rq[0] * (1.f / C_) - mu * mu;
  float rstd = rsqrtf(var + 1e-5f);
  bf16* q = out + (size_t)row * C_;
  q[tid] = (bf16)((v0 - mu) * rstd * g[tid] + be[tid]);
  q[tid + 256] = (bf16)((v1 - mu) * rstd * g[tid + 256] + be[tid + 256]);
  q[tid + 512] = (bf16)((v2 - mu) * rstd * g[tid + 512] + be[tid + 512]);
}

// ---------------------------------------------------------------------------
extern "C" void kernel_launch(void* const* d_in, const int* in_sizes, int n_in,
                              void* d_out, int out_size, void* d_ws,
                              size_t ws_size, hipStream_t stream) {
  (void)in_sizes; (void)n_in; (void)out_size; (void)ws_size;
  const float* x      = (const float*)d_in[0];
  const float* conv_w = (const float*)d_in[1];
  const float* conv_b = (const float*)d_in[2];
  const float* ln1_g  = (const float*)d_in[3];
  const float* ln1_b  = (const float*)d_in[4];
  const float* qkv_w  = (const float*)d_in[5];
  const float* proj_w = (const float*)d_in[6];
  const float* proj_b = (const float*)d_in[7];
  const float* ln2_g  = (const float*)d_in[8];
  const float* ln2_b  = (const float*)d_in[9];
  const float* fc1_w  = (const float*)d_in[10];
  const float* fc1_b  = (const float*)d_in[11];
  const float* fc2_w  = (const float*)d_in[12];
  const float* fc2_b  = (const float*)d_in[13];
  float* out = (float*)d_out;

  char* w = (char*)d_ws;
  auto carve = [&](size_t bytes) {
    char* p = w;
    w += (bytes + 255) & ~(size_t)255;
    return p;
  };
  bf16* hid   = (bf16*)carve((size_t)NTOK * HID_ * 2);
  float* t0   = (float*)carve((size_t)NTOK * C_ * 4);
  bf16* lnout = (bf16*)carve((size_t)NTOK * C_ * 2);
  bf16* wq    = (bf16*)carve((size_t)3 * C_ * C_ * 2);
  bf16* wp    = (bf16*)carve((size_t)C_ * C_ * 2);
  bf16* w1    = (bf16*)carve((size_t)HID_ * C_ * 2);
  bf16* w2    = (bf16*)carve((size_t)C_ * HID_ * 2);
  bf16* Qb    = (bf16*)carve((size_t)NHEADS * N_ * HD_ * 2);
  bf16* Kb    = (bf16*)carve((size_t)NHEADS * N_ * HD_ * 2);
  bf16* Vt    = (bf16*)carve((size_t)NHEADS * HD_ * N_ * 2);
  bf16* attn  = (bf16*)carve((size_t)NTOK * C_ * 2);

  const int na = 3 * C_ * C_, nb = C_ * C_, nc = HID_ * C_, nd = C_ * HID_;
  cast_all<<<(na + nb + nc + nd) / 1024, 256, 0, stream>>>(
      qkv_w, na, proj_w, nb, fc1_w, nc, fc2_w, wq);

  conv_pe_t<<<dim3(32, C_ / 32, B_), 256, 0, stream>>>(x, conv_w, conv_b, t0);

  // QKV: 18 n-tiles x 64 m-stripes, XCD remap
  ln_bf16<<<NTOK, 256, 0, stream>>>(t0, ln1_g, ln1_b, lnout);
  gemm_bt<128, 0, true><<<1152, 256, 0, stream>>>(
      lnout, wq, 768, 768, 768, 18, Qb, Kb, Vt, nullptr, nullptr, nullptr);

  flash_attn<<<dim3(N_ / 128, NHEADS), 256, 0, stream>>>(Qb, Kb, Vt, attn);

  // proj: 12 n-tiles (BN=64), fc1: 24 n-tiles (BN=128), fc2: 12 (BN=64, NCHW)
  gemm_bt<64, 3, true><<<768, 256, 0, stream>>>(
      attn, wp, 768, 768, 768, 12, nullptr, nullptr, nullptr, t0, proj_b,
      nullptr);
  ln_bf16<<<NTOK, 256, 0, stream>>>(t0, ln2_g, ln2_b, lnout);
  gemm_bt<128, 4, true><<<1536, 256, 0, stream>>>(
      lnout, w1, 768, 768, 768, 24, hid, nullptr, nullptr, nullptr, fc1_b,
      nullptr);
  gemm_bt<64, 5, true><<<768, 256, 0, stream>>>(
      hid, w2, 3072, 3072, 3072, 12, nullptr, nullptr, nullptr, t0, fc2_b,
      out);
}